// Round 2
// baseline (566.776 us; speedup 1.0000x reference)
//
#include <hip/hip_runtime.h>

#define DEV __device__ __forceinline__

typedef __bf16 bf16x8 __attribute__((ext_vector_type(8)));
typedef float f32x4 __attribute__((ext_vector_type(4)));

// ---- constants ----
#define BB 4
#define LL 2048
#define DMODEL 1024
#define DINNER 2048
#define NHEADS 16
#define HEADDIM 128
#define DSTATE 64
#define CONVDIM 2176
#define DINPROJ 4240
#define NPAD 4352
#define NCHUNK 32
#define ROWS (BB*LL)   // 8192

// ---- workspace offsets (bytes) ----
#define OF_H32 ((size_t)0)                       // 8192*1024*4 = 33554432
#define OF_HBF ((size_t)33554432)                // 16777216
#define OF_WI  ((size_t)50331648)                // 4352*1024*2 = 8912896
#define OF_Y   ((size_t)0)                       // 8192*2048*4 = 67108864 (overlays h32/hbf/Wi)
#define OF_WO  ((size_t)67108864)                // 1024*2048*2 = 4194304
#define OF_Z   ((size_t)71303168)                // 8192*4352*2 = 71303168
#define OF_DT  ((size_t)142606336)               // 8192*16*4 = 524288
#define OF_CONV ((size_t)143130624)              // 8192*2176*2 = 35651584
#define OF_YBF  OF_CONV                          // 8192*2048*2 = 33554432 (overlays conv)
#define OF_SP  ((size_t)178782208)               // 4*32*16*128*64*2 = 33554432
#define OF_ACS ((size_t)212336640)               // 4*16*32*64*4 = 524288
#define OF_ECS ((size_t)212860928)               // 4*16*32*4 = 8192

DEV void gload_lds16(const void* g, void* l) {
  __builtin_amdgcn_global_load_lds((const __attribute__((address_space(1))) void*)g,
                                   (__attribute__((address_space(3))) void*)l, 16, 0, 0);
}

// ---- K0: weight conversion fp32 -> bf16 (W_in padded to 4352 rows) ----
__global__ __launch_bounds__(256) void convert_w_kernel(
    const float* __restrict__ Wi, const float* __restrict__ Wo,
    __bf16* __restrict__ Wib, __bf16* __restrict__ Wob)
{
  const int NI = NPAD * DMODEL;        // 4456448
  const int NIr = DINPROJ * DMODEL;    // 4341760
  const int NO = DMODEL * DINNER;      // 2097152
  for (int i = blockIdx.x * 256 + threadIdx.x; i < NI + NO; i += gridDim.x * 256) {
    if (i < NI) Wib[i] = (i < NIr) ? (__bf16)Wi[i] : (__bf16)0.f;
    else        Wob[i - NI] = (__bf16)Wo[i - NI];
  }
}

// ---- K1: embed + layernorm -> h (f32 + bf16) ----
__global__ __launch_bounds__(256) void embed_ln_kernel(
    const float* __restrict__ x, const float* __restrict__ w,
    const float* __restrict__ g, const float* __restrict__ bta,
    float* __restrict__ h32, __bf16* __restrict__ hbf)
{
  int row = blockIdx.x, t = threadIdx.x;
  float xv = x[row];
  float v[4]; float s = 0.f, s2 = 0.f;
  #pragma unroll
  for (int j = 0; j < 4; j++) {
    int i = t + j * 256;
    float hv = xv * w[i];
    v[j] = hv; s += hv; s2 += hv * hv;
  }
  #pragma unroll
  for (int m = 32; m; m >>= 1) { s += __shfl_xor(s, m); s2 += __shfl_xor(s2, m); }
  __shared__ float rs[4], rs2[4];
  if ((t & 63) == 0) { rs[t >> 6] = s; rs2[t >> 6] = s2; }
  __syncthreads();
  s = rs[0] + rs[1] + rs[2] + rs[3];
  s2 = rs2[0] + rs2[1] + rs2[2] + rs2[3];
  float mu = s * (1.f / DMODEL);
  float var = s2 * (1.f / DMODEL) - mu * mu;
  float r = rsqrtf(var + 1e-5f);
  #pragma unroll
  for (int j = 0; j < 4; j++) {
    int i = t + j * 256;
    float o = (v[j] - mu) * r * g[i] + bta[i];
    h32[(size_t)row * DMODEL + i] = o;
    hbf[(size_t)row * DMODEL + i] = (__bf16)o;
  }
}

// ---- K2/K9: bf16 MFMA GEMM, C[M,N] = A[M,K] @ Bt[N,K]^T ----
// grid = (N/128, M/128), block 256 (4 waves in 2x2), m97 structure
template <typename OutT>
__global__ __launch_bounds__(256) void gemm_bt_kernel(
    const __bf16* __restrict__ A, const __bf16* __restrict__ Bt,
    OutT* __restrict__ C, int K, int ldc)
{
  __shared__ __bf16 As[128 * 32];
  __shared__ __bf16 Bs[128 * 32];
  int t = threadIdx.x;
  int lane = t & 63, wave = t >> 6;
  int m0 = blockIdx.y * 128, n0 = blockIdx.x * 128;
  int wm = (wave >> 1) * 64, wn = (wave & 1) * 64;
  f32x4 acc[4][4] = {};
  int sr = t >> 2;            // staging row 0..63
  int sc = (t & 3) << 3;      // staging k offset
  const __bf16* aS = A + (size_t)(m0 + sr) * K + sc;
  const __bf16* bS = Bt + (size_t)(n0 + sr) * K + sc;
  int lr = lane & 15;
  int kb = (lane >> 4) << 3;
  const __bf16* Ap = &As[0] + (wm + lr) * 32 + kb;
  const __bf16* Bp = &Bs[0] + (wn + lr) * 32 + kb;
  for (int k0 = 0; k0 < K; k0 += 32) {
    gload_lds16(aS + k0, &As[8 * t]);
    gload_lds16(aS + (size_t)64 * K + k0, &As[2048 + 8 * t]);
    gload_lds16(bS + k0, &Bs[8 * t]);
    gload_lds16(bS + (size_t)64 * K + k0, &Bs[2048 + 8 * t]);
    __syncthreads();
    bf16x8 af[4], bfr[4];
    #pragma unroll
    for (int i = 0; i < 4; i++) af[i] = *(const bf16x8*)(Ap + i * 16 * 32);
    #pragma unroll
    for (int j = 0; j < 4; j++) bfr[j] = *(const bf16x8*)(Bp + j * 16 * 32);
    #pragma unroll
    for (int i = 0; i < 4; i++)
      #pragma unroll
      for (int j = 0; j < 4; j++)
        acc[i][j] = __builtin_amdgcn_mfma_f32_16x16x32_bf16(af[i], bfr[j], acc[i][j], 0, 0, 0);
    __syncthreads();
  }
  int orow = m0 + wm + (lane >> 4) * 4;
  int ocol = n0 + wn + (lane & 15);
  #pragma unroll
  for (int i = 0; i < 4; i++)
    #pragma unroll
    for (int j = 0; j < 4; j++)
      #pragma unroll
      for (int q = 0; q < 4; q++)
        C[(size_t)(orow + i * 16 + q) * ldc + ocol + j * 16] = (OutT)acc[i][j][q];
}

// ---- K3: fp32 dt recompute (16 cols of in_proj) + softplus ----
__global__ __launch_bounds__(256) void dt_kernel(
    const float* __restrict__ h32, const float* __restrict__ W_in,
    const float* __restrict__ dt_bias, float* __restrict__ dtb)
{
  int row = blockIdx.x, t = threadIdx.x;
  __shared__ float hs[DMODEL];
  #pragma unroll
  for (int j = 0; j < 4; j++) hs[t + j * 256] = h32[(size_t)row * DMODEL + t + j * 256];
  __syncthreads();
  int head = t >> 4, l16 = t & 15;
  const float* wr = W_in + (size_t)(DINNER + CONVDIM + head) * DMODEL; // row 4224+head
  float acc = 0.f;
  #pragma unroll 4
  for (int j = 0; j < 64; j++) {
    int k = j * 16 + l16;
    acc += hs[k] * wr[k];
  }
  #pragma unroll
  for (int m = 8; m; m >>= 1) acc += __shfl_xor(acc, m, 16);
  if (l16 == 0) {
    float vx = acc + dt_bias[head];
    float dt = vx > 15.f ? vx : log1pf(__expf(vx));
    dtb[(size_t)row * NHEADS + head] = dt;
  }
}

// ---- K4: causal depthwise conv1d + silu ----
__global__ __launch_bounds__(256) void conv_kernel(
    const __bf16* __restrict__ Z, const float* __restrict__ conv_w,
    const float* __restrict__ conv_b, __bf16* __restrict__ out)
{
  int idx = blockIdx.x * 256 + threadIdx.x;
  if (idx >= ROWS * CONVDIM) return;
  int ch = idx % CONVDIM;
  int row = idx / CONVDIM;
  int l = row & (LL - 1), b = row >> 11;
  float acc = conv_b[ch];
  #pragma unroll
  for (int k = 0; k < 4; k++) {
    int li = l + k - 3;
    if (li >= 0)
      acc += (float)Z[(size_t)(b * LL + li) * NPAD + DINNER + ch] * conv_w[ch * 4 + k];
  }
  float s = acc / (1.f + __expf(-acc));
  out[(size_t)row * CONVDIM + ch] = (__bf16)s;
}

// ---- K5: per-chunk intra: Acs, Y_diag, chunk states ----
__global__ __launch_bounds__(256) void ssd_chunk_kernel(
    const __bf16* __restrict__ conv, const float* __restrict__ dtb,
    const float* __restrict__ A_log, float* __restrict__ Y,
    __bf16* __restrict__ S, float* __restrict__ acs, float* __restrict__ ecs)
{
  int bx = blockIdx.x;
  int c = bx & 31, h = (bx >> 5) & 15, b = bx >> 9;
  int t = threadIdx.x;
  __shared__ __bf16 Bsm[64][68];
  __shared__ __bf16 Csm[64][68];
  __shared__ float Xs[64][128];
  __shared__ __bf16 Gs[64][66];
  __shared__ float sAcs[64], sDec[64], sDt[64];
  int row0 = b * LL + c * 64;
  for (int i = t; i < 64 * 64; i += 256) {
    int l = i >> 6, n = i & 63;
    const __bf16* rp = conv + (size_t)(row0 + l) * CONVDIM;
    Bsm[l][n] = rp[DINNER + n];
    Csm[l][n] = rp[DINNER + DSTATE + n];
  }
  if (t < 64) sDt[t] = dtb[(size_t)(row0 + t) * NHEADS + h];
  __syncthreads();
  if (t == 0) {
    float Ah = -__expf(A_log[h]);
    float cs = 0.f;
    for (int l = 0; l < 64; l++) { cs += sDt[l] * Ah; sAcs[l] = cs; }
  }
  for (int i = t; i < 64 * 128; i += 256) {
    int l = i >> 7, p = i & 127;
    Xs[l][p] = (float)conv[(size_t)(row0 + l) * CONVDIM + h * HEADDIM + p] * sDt[l];
  }
  __syncthreads();
  float csEnd = sAcs[63];
  if (t < 64) {
    sDec[t] = __expf(csEnd - sAcs[t]);
    acs[(((size_t)b * NHEADS + h) * NCHUNK + c) * 64 + t] = sAcs[t];
  }
  if (t == 0) ecs[((size_t)b * NHEADS + h) * NCHUNK + c] = __expf(csEnd);
  // G = tril(C @ B^T) * exp(Acs[l]-Acs[s])
  {
    int l0 = (t >> 4) * 4, s0 = (t & 15) * 4;
    float g[4][4] = {};
    #pragma unroll 4
    for (int n = 0; n < 64; n++) {
      float cv[4], bv[4];
      #pragma unroll
      for (int i = 0; i < 4; i++) cv[i] = (float)Csm[l0 + i][n];
      #pragma unroll
      for (int j = 0; j < 4; j++) bv[j] = (float)Bsm[s0 + j][n];
      #pragma unroll
      for (int i = 0; i < 4; i++)
        #pragma unroll
        for (int j = 0; j < 4; j++) g[i][j] += cv[i] * bv[j];
    }
    #pragma unroll
    for (int i = 0; i < 4; i++)
      #pragma unroll
      for (int j = 0; j < 4; j++) {
        int l = l0 + i, s = s0 + j;
        float val = (l >= s) ? g[i][j] * __expf(sAcs[l] - sAcs[s]) : 0.f;
        Gs[l][s] = (__bf16)val;
      }
  }
  __syncthreads();
  // Y_diag = G @ X
  {
    int l0 = (t >> 4) * 4, p0 = (t & 15) * 8;
    float y[4][8] = {};
    #pragma unroll 4
    for (int s = 0; s < 64; s++) {
      float gv[4], xv[8];
      #pragma unroll
      for (int i = 0; i < 4; i++) gv[i] = (float)Gs[l0 + i][s];
      #pragma unroll
      for (int j = 0; j < 8; j++) xv[j] = Xs[s][p0 + j];
      #pragma unroll
      for (int i = 0; i < 4; i++)
        #pragma unroll
        for (int j = 0; j < 8; j++) y[i][j] += gv[i] * xv[j];
    }
    #pragma unroll
    for (int i = 0; i < 4; i++)
      #pragma unroll
      for (int j = 0; j < 8; j++)
        Y[(size_t)(row0 + l0 + i) * DINNER + h * HEADDIM + p0 + j] = y[i][j];
  }
  // states S[p][n] = sum_l X[l][p]*dec[l]*B[l][n]
  {
    int p0 = (t >> 4) * 8, n0 = (t & 15) * 4;
    float sv[8][4] = {};
    #pragma unroll 4
    for (int l = 0; l < 64; l++) {
      float d = sDec[l];
      float xv[8], bv[4];
      #pragma unroll
      for (int i = 0; i < 8; i++) xv[i] = Xs[l][p0 + i] * d;
      #pragma unroll
      for (int j = 0; j < 4; j++) bv[j] = (float)Bsm[l][n0 + j];
      #pragma unroll
      for (int i = 0; i < 8; i++)
        #pragma unroll
        for (int j = 0; j < 4; j++) sv[i][j] += xv[i] * bv[j];
    }
    __bf16* Sp = S + (((size_t)b * NCHUNK + c) * NHEADS + h) * (HEADDIM * DSTATE);
    #pragma unroll
    for (int i = 0; i < 8; i++)
      #pragma unroll
      for (int j = 0; j < 4; j++)
        Sp[(p0 + i) * DSTATE + n0 + j] = (__bf16)sv[i][j];
  }
}

// ---- K6: inter-chunk scan, in-place S -> prev_states ----
__global__ __launch_bounds__(256) void scan_kernel(
    __bf16* SP, const float* __restrict__ ecs)
{
  int t = blockIdx.x * 256 + threadIdx.x;       // 524288 = B*H*P*N
  int n = t & 63, p = (t >> 6) & 127, h = (t >> 13) & 15, b = t >> 17;
  float P = 0.f;
  for (int c = 0; c < NCHUNK; c++) {
    size_t idx = (((size_t)b * NCHUNK + c) * NHEADS + h) * (HEADDIM * DSTATE) + (size_t)p * DSTATE + n;
    float s = (float)SP[idx];
    SP[idx] = (__bf16)P;
    float e = ecs[((size_t)b * NHEADS + h) * NCHUNK + c];
    P = e * P + s;
  }
}

// ---- K7: Y += exp(Acs[l]) * (C @ P^T) + D * x ----
__global__ __launch_bounds__(256) void ssd_off_kernel(
    const __bf16* __restrict__ conv, const __bf16* __restrict__ P,
    const float* __restrict__ acs, const float* __restrict__ Dp,
    float* __restrict__ Y)
{
  int bx = blockIdx.x;
  int c = bx & 31, h = (bx >> 5) & 15, b = bx >> 9;
  int t = threadIdx.x;
  __shared__ __bf16 Csm[64][68];
  __shared__ float Ps[128][65];
  __shared__ float eA[64];
  int row0 = b * LL + c * 64;
  for (int i = t; i < 64 * 64; i += 256) {
    int l = i >> 6, n = i & 63;
    Csm[l][n] = conv[(size_t)(row0 + l) * CONVDIM + DINNER + DSTATE + n];
  }
  const __bf16* Pp = P + (((size_t)b * NCHUNK + c) * NHEADS + h) * (HEADDIM * DSTATE);
  for (int i = t; i < 128 * 64; i += 256) Ps[i >> 6][i & 63] = (float)Pp[i];
  if (t < 64) eA[t] = __expf(acs[(((size_t)b * NHEADS + h) * NCHUNK + c) * 64 + t]);
  __syncthreads();
  int l0 = (t >> 4) * 4, p0 = (t & 15) * 8;
  float y[4][8] = {};
  #pragma unroll 4
  for (int n = 0; n < 64; n++) {
    float cv[4], pv[8];
    #pragma unroll
    for (int i = 0; i < 4; i++) cv[i] = (float)Csm[l0 + i][n];
    #pragma unroll
    for (int j = 0; j < 8; j++) pv[j] = Ps[p0 + j][n];
    #pragma unroll
    for (int i = 0; i < 4; i++)
      #pragma unroll
      for (int j = 0; j < 8; j++) y[i][j] += cv[i] * pv[j];
  }
  float Dh = Dp[h];
  #pragma unroll
  for (int i = 0; i < 4; i++) {
    int l = l0 + i;
    #pragma unroll
    for (int j = 0; j < 8; j++) {
      size_t yi = (size_t)(row0 + l) * DINNER + h * HEADDIM + p0 + j;
      float xsv = (float)conv[(size_t)(row0 + l) * CONVDIM + h * HEADDIM + p0 + j];
      Y[yi] += eA[l] * y[i][j] + Dh * xsv;
    }
  }
}

// ---- K8: y *= silu(z); RMSNorm; -> bf16 ----
__global__ __launch_bounds__(256) void gate_norm_kernel(
    const float* __restrict__ Y, const __bf16* __restrict__ Z,
    const float* __restrict__ rms_w, __bf16* __restrict__ ybf)
{
  int row = blockIdx.x, t = threadIdx.x;
  float v[8]; float ss = 0.f;
  #pragma unroll
  for (int j = 0; j < 8; j++) {
    int i = t + j * 256;
    float zv = (float)Z[(size_t)row * NPAD + i];
    float yv = Y[(size_t)row * DINNER + i];
    float g = yv * (zv / (1.f + __expf(-zv)));
    v[j] = g; ss += g * g;
  }
  #pragma unroll
  for (int m = 32; m; m >>= 1) ss += __shfl_xor(ss, m);
  __shared__ float red[4];
  if ((t & 63) == 0) red[t >> 6] = ss;
  __syncthreads();
  float tot = red[0] + red[1] + red[2] + red[3];
  float r = rsqrtf(tot * (1.f / DINNER) + 1e-5f);
  #pragma unroll
  for (int j = 0; j < 8; j++) {
    int i = t + j * 256;
    ybf[(size_t)row * DINNER + i] = (__bf16)(v[j] * r * rms_w[i]);
  }
}

extern "C" void kernel_launch(void* const* d_in, const int* in_sizes, int n_in,
                              void* d_out, int out_size, void* d_ws, size_t ws_size,
                              hipStream_t stream) {
  const float* x       = (const float*)d_in[0];
  const float* w_embed = (const float*)d_in[1];
  const float* ln_g    = (const float*)d_in[2];
  const float* ln_b    = (const float*)d_in[3];
  const float* W_in    = (const float*)d_in[4];
  const float* conv_w  = (const float*)d_in[5];
  const float* conv_b  = (const float*)d_in[6];
  const float* dt_bias = (const float*)d_in[7];
  const float* A_log   = (const float*)d_in[8];
  const float* Dp      = (const float*)d_in[9];
  const float* rms_w   = (const float*)d_in[10];
  const float* W_out   = (const float*)d_in[11];
  char* ws = (char*)d_ws;
  float*  h32  = (float*)(ws + OF_H32);
  __bf16* hbf  = (__bf16*)(ws + OF_HBF);
  __bf16* Wib  = (__bf16*)(ws + OF_WI);
  __bf16* Wob  = (__bf16*)(ws + OF_WO);
  __bf16* Zbf  = (__bf16*)(ws + OF_Z);
  float*  dtb  = (float*)(ws + OF_DT);
  __bf16* convb = (__bf16*)(ws + OF_CONV);
  __bf16* SP   = (__bf16*)(ws + OF_SP);
  float*  acs  = (float*)(ws + OF_ACS);
  float*  ecs  = (float*)(ws + OF_ECS);
  float*  Y    = (float*)(ws + OF_Y);
  __bf16* ybf  = (__bf16*)(ws + OF_YBF);
  float*  out  = (float*)d_out;

  convert_w_kernel<<<2048, 256, 0, stream>>>(W_in, W_out, Wib, Wob);
  embed_ln_kernel<<<ROWS, 256, 0, stream>>>(x, w_embed, ln_g, ln_b, h32, hbf);
  gemm_bt_kernel<__bf16><<<dim3(NPAD / 128, ROWS / 128), 256, 0, stream>>>(hbf, Wib, Zbf, DMODEL, NPAD);
  dt_kernel<<<ROWS, 256, 0, stream>>>(h32, W_in, dt_bias, dtb);
  conv_kernel<<<(ROWS * CONVDIM) / 256, 256, 0, stream>>>(Zbf, conv_w, conv_b, convb);
  ssd_chunk_kernel<<<BB * NHEADS * NCHUNK, 256, 0, stream>>>(convb, dtb, A_log, Y, SP, acs, ecs);
  scan_kernel<<<(BB * NHEADS * HEADDIM * DSTATE) / 256, 256, 0, stream>>>(SP, ecs);
  ssd_off_kernel<<<BB * NHEADS * NCHUNK, 256, 0, stream>>>(convb, SP, acs, Dp, Y);
  gate_norm_kernel<<<ROWS, 256, 0, stream>>>(Y, Zbf, rms_w, ybf);
  gemm_bt_kernel<float><<<dim3(DMODEL / 128, ROWS / 128), 256, 0, stream>>>(ybf, Wob, out, DINNER, DMODEL);
}

// Round 3
// 483.106 us; speedup vs baseline: 1.1732x; 1.1732x over previous
//
#include <hip/hip_runtime.h>

#define DEV __device__ __forceinline__

typedef __bf16 bf16x8 __attribute__((ext_vector_type(8)));
typedef float f32x4 __attribute__((ext_vector_type(4)));

// ---- constants ----
#define BB 4
#define LL 2048
#define DMODEL 1024
#define DINNER 2048
#define NHEADS 16
#define HEADDIM 128
#define DSTATE 64
#define CONVDIM 2176
#define DINPROJ 4240
#define NPAD 4352
#define NCHUNK 32
#define ROWS (BB*LL)   // 8192

// ---- workspace offsets (bytes) ----
#define OF_H32 ((size_t)0)                       // 8192*1024*4 = 33554432
#define OF_HBF ((size_t)33554432)                // 16777216
#define OF_WI  ((size_t)50331648)                // 4352*1024*2 = 8912896
#define OF_Y   ((size_t)0)                       // 8192*2048*4 = 67108864 (overlays h32/hbf/Wi)
#define OF_WO  ((size_t)67108864)                // 1024*2048*2 = 4194304
#define OF_Z   ((size_t)71303168)                // 8192*4352*2 = 71303168
#define OF_DT  ((size_t)142606336)               // 8192*16*4 = 524288
#define OF_CONV ((size_t)143130624)              // 8192*2176*2 = 35651584
#define OF_YBF  OF_CONV                          // 8192*2048*2 = 33554432 (overlays conv)
#define OF_SP  ((size_t)178782208)               // 4*32*16*128*64*2 = 33554432
#define OF_ACS ((size_t)212336640)               // 4*16*32*64*4 = 524288
#define OF_ECS ((size_t)212860928)               // 4*16*32*4 = 8192

DEV void gload_lds16(const void* g, void* l) {
  __builtin_amdgcn_global_load_lds((const __attribute__((address_space(1))) void*)g,
                                   (__attribute__((address_space(3))) void*)l, 16, 0, 0);
}

// XOR-swizzled byte address within a [R][64] bf16 tile (rows = 128 B).
// For b128 ops c must be a multiple of 8 (XOR touches byte bits 4..6 only).
DEV char* swaddr(char* base, int r, int c) {
  return base + r * 128 + (((c) * 2) ^ (((r) & 7) << 4));
}

// ---- K0: weight conversion fp32 -> bf16 (W_in padded to 4352 rows) ----
__global__ __launch_bounds__(256) void convert_w_kernel(
    const float* __restrict__ Wi, const float* __restrict__ Wo,
    __bf16* __restrict__ Wib, __bf16* __restrict__ Wob)
{
  const int NI = NPAD * DMODEL;        // 4456448
  const int NIr = DINPROJ * DMODEL;    // 4341760
  const int NO = DMODEL * DINNER;      // 2097152
  for (int i = blockIdx.x * 256 + threadIdx.x; i < NI + NO; i += gridDim.x * 256) {
    if (i < NI) Wib[i] = (i < NIr) ? (__bf16)Wi[i] : (__bf16)0.f;
    else        Wob[i - NI] = (__bf16)Wo[i - NI];
  }
}

// ---- K1: embed + layernorm -> h (f32 + bf16) ----
__global__ __launch_bounds__(256) void embed_ln_kernel(
    const float* __restrict__ x, const float* __restrict__ w,
    const float* __restrict__ g, const float* __restrict__ bta,
    float* __restrict__ h32, __bf16* __restrict__ hbf)
{
  int row = blockIdx.x, t = threadIdx.x;
  float xv = x[row];
  float v[4]; float s = 0.f, s2 = 0.f;
  #pragma unroll
  for (int j = 0; j < 4; j++) {
    int i = t + j * 256;
    float hv = xv * w[i];
    v[j] = hv; s += hv; s2 += hv * hv;
  }
  #pragma unroll
  for (int m = 32; m; m >>= 1) { s += __shfl_xor(s, m); s2 += __shfl_xor(s2, m); }
  __shared__ float rs[4], rs2[4];
  if ((t & 63) == 0) { rs[t >> 6] = s; rs2[t >> 6] = s2; }
  __syncthreads();
  s = rs[0] + rs[1] + rs[2] + rs[3];
  s2 = rs2[0] + rs2[1] + rs2[2] + rs2[3];
  float mu = s * (1.f / DMODEL);
  float var = s2 * (1.f / DMODEL) - mu * mu;
  float r = rsqrtf(var + 1e-5f);
  #pragma unroll
  for (int j = 0; j < 4; j++) {
    int i = t + j * 256;
    float o = (v[j] - mu) * r * g[i] + bta[i];
    h32[(size_t)row * DMODEL + i] = o;
    hbf[(size_t)row * DMODEL + i] = (__bf16)o;
  }
}

// ---- K2/K9: bf16 MFMA GEMM, C[M,N] = A[M,K] @ Bt[N,K]^T ----
template <typename OutT>
__global__ __launch_bounds__(256) void gemm_bt_kernel(
    const __bf16* __restrict__ A, const __bf16* __restrict__ Bt,
    OutT* __restrict__ C, int K, int ldc)
{
  __shared__ __bf16 As[128 * 32];
  __shared__ __bf16 Bs[128 * 32];
  int t = threadIdx.x;
  int lane = t & 63, wave = t >> 6;
  int m0 = blockIdx.y * 128, n0 = blockIdx.x * 128;
  int wm = (wave >> 1) * 64, wn = (wave & 1) * 64;
  f32x4 acc[4][4] = {};
  int sr = t >> 2;            // staging row 0..63
  int sc = (t & 3) << 3;      // staging k offset
  const __bf16* aS = A + (size_t)(m0 + sr) * K + sc;
  const __bf16* bS = Bt + (size_t)(n0 + sr) * K + sc;
  int lr = lane & 15;
  int kb = (lane >> 4) << 3;
  const __bf16* Ap = &As[0] + (wm + lr) * 32 + kb;
  const __bf16* Bp = &Bs[0] + (wn + lr) * 32 + kb;
  for (int k0 = 0; k0 < K; k0 += 32) {
    gload_lds16(aS + k0, &As[8 * t]);
    gload_lds16(aS + (size_t)64 * K + k0, &As[2048 + 8 * t]);
    gload_lds16(bS + k0, &Bs[8 * t]);
    gload_lds16(bS + (size_t)64 * K + k0, &Bs[2048 + 8 * t]);
    __syncthreads();
    bf16x8 af[4], bfr[4];
    #pragma unroll
    for (int i = 0; i < 4; i++) af[i] = *(const bf16x8*)(Ap + i * 16 * 32);
    #pragma unroll
    for (int j = 0; j < 4; j++) bfr[j] = *(const bf16x8*)(Bp + j * 16 * 32);
    #pragma unroll
    for (int i = 0; i < 4; i++)
      #pragma unroll
      for (int j = 0; j < 4; j++)
        acc[i][j] = __builtin_amdgcn_mfma_f32_16x16x32_bf16(af[i], bfr[j], acc[i][j], 0, 0, 0);
    __syncthreads();
  }
  int orow = m0 + wm + (lane >> 4) * 4;
  int ocol = n0 + wn + (lane & 15);
  #pragma unroll
  for (int i = 0; i < 4; i++)
    #pragma unroll
    for (int j = 0; j < 4; j++)
      #pragma unroll
      for (int q = 0; q < 4; q++)
        C[(size_t)(orow + i * 16 + q) * ldc + ocol + j * 16] = (OutT)acc[i][j][q];
}

// ---- K3: fp32 dt recompute (16 cols of in_proj) + softplus ----
__global__ __launch_bounds__(256) void dt_kernel(
    const float* __restrict__ h32, const float* __restrict__ W_in,
    const float* __restrict__ dt_bias, float* __restrict__ dtb)
{
  int row = blockIdx.x, t = threadIdx.x;
  __shared__ float hs[DMODEL];
  #pragma unroll
  for (int j = 0; j < 4; j++) hs[t + j * 256] = h32[(size_t)row * DMODEL + t + j * 256];
  __syncthreads();
  int head = t >> 4, l16 = t & 15;
  const float* wr = W_in + (size_t)(DINNER + CONVDIM + head) * DMODEL; // row 4224+head
  float acc = 0.f;
  #pragma unroll 4
  for (int j = 0; j < 64; j++) {
    int k = j * 16 + l16;
    acc += hs[k] * wr[k];
  }
  #pragma unroll
  for (int m = 8; m; m >>= 1) acc += __shfl_xor(acc, m, 16);
  if (l16 == 0) {
    float vx = acc + dt_bias[head];
    float dt = vx > 15.f ? vx : log1pf(__expf(vx));
    dtb[(size_t)row * NHEADS + head] = dt;
  }
}

// ---- K4: causal depthwise conv1d + silu ----
__global__ __launch_bounds__(256) void conv_kernel(
    const __bf16* __restrict__ Z, const float* __restrict__ conv_w,
    const float* __restrict__ conv_b, __bf16* __restrict__ out)
{
  int idx = blockIdx.x * 256 + threadIdx.x;
  if (idx >= ROWS * CONVDIM) return;
  int ch = idx % CONVDIM;
  int row = idx / CONVDIM;
  int l = row & (LL - 1), b = row >> 11;
  float acc = conv_b[ch];
  #pragma unroll
  for (int k = 0; k < 4; k++) {
    int li = l + k - 3;
    if (li >= 0)
      acc += (float)Z[(size_t)(b * LL + li) * NPAD + DINNER + ch] * conv_w[ch * 4 + k];
  }
  float s = acc / (1.f + __expf(-acc));
  out[(size_t)row * CONVDIM + ch] = (__bf16)s;
}

// ---- K5: per-chunk intra (MFMA): Acs, G, Y_diag, chunk states ----
// LDS tiles (all [*][64] bf16, XOR-swizzled):
//   Csm (A-op of G), Bsm (B-op of G), BdT[n][l]=dec[l]*B[l][n] (B-op of S),
//   Gs (A-op of Y), XT[p][l]=X[l][p]*dt[l] (B-op of Y AND A-op of S)
__global__ __launch_bounds__(256) void ssd_chunk_kernel(
    const __bf16* __restrict__ conv, const float* __restrict__ dtb,
    const float* __restrict__ A_log, float* __restrict__ Y,
    __bf16* __restrict__ S, float* __restrict__ acs, float* __restrict__ ecs)
{
  __shared__ __align__(16) char sm[49664];
  char* smC  = sm;             // [64][64]
  char* smB  = sm + 8192;      // [64][64]
  char* smBd = sm + 16384;     // [64][64] (rows n, cols l)
  char* smG  = sm + 24576;     // [64][64]
  char* smX  = sm + 32768;     // [128][64] (rows p, cols l)
  float* sAcs = (float*)(sm + 49152);
  float* sDec = (float*)(sm + 49408);

  int bx = blockIdx.x;
  int c = bx & 31, h = (bx >> 5) & 15, b = bx >> 9;
  int t = threadIdx.x;
  int lane = t & 63, w = t >> 6;
  int row0 = b * LL + c * 64;
  const __bf16* cr = conv + (size_t)(row0 + lane) * CONVDIM;
  float dtv = dtb[(size_t)(row0 + lane) * NHEADS + h];

  // per-thread global reads (lane = row l, wave picks column chunk)
  bf16x8 bch[2], cch[2], xch[4];
  #pragma unroll
  for (int k = 0; k < 2; k++) {
    int c8 = w * 16 + 8 * k;
    bch[k] = *(const bf16x8*)(cr + DINNER + c8);
    cch[k] = *(const bf16x8*)(cr + DINNER + DSTATE + c8);
  }
  #pragma unroll
  for (int k = 0; k < 4; k++)
    xch[k] = *(const bf16x8*)(cr + h * HEADDIM + w * 8 + 32 * k);

  // wave 0: parallel inclusive scan of dA -> Acs, dec, global acs/ecs
  if (t < 64) {
    float Ah = -__expf(A_log[h]);
    float cs = dtv * Ah;
    #pragma unroll
    for (int off = 1; off < 64; off <<= 1) {
      float o = __shfl_up(cs, off);
      if (lane >= off) cs += o;
    }
    float cend = __shfl(cs, 63);
    sAcs[lane] = cs;
    sDec[lane] = __expf(cend - cs);
    acs[(((size_t)b * NHEADS + h) * NCHUNK + c) * 64 + lane] = cs;
    if (lane == 63) ecs[((size_t)b * NHEADS + h) * NCHUNK + c] = __expf(cend);
  }

  // LDS writes: Bsm/Csm (b128, swz, conflict-free), XT transpose (b16, lane-major rows)
  #pragma unroll
  for (int k = 0; k < 2; k++) {
    int c8 = w * 16 + 8 * k;
    *(bf16x8*)swaddr(smB, lane, c8) = bch[k];
    *(bf16x8*)swaddr(smC, lane, c8) = cch[k];
  }
  #pragma unroll
  for (int k = 0; k < 4; k++) {
    int p0 = w * 8 + 32 * k;
    #pragma unroll
    for (int j = 0; j < 8; j++)
      *(__bf16*)swaddr(smX, p0 + j, lane) = (__bf16)((float)xch[k][j] * dtv);
  }
  __syncthreads();

  // BdT[n][l] = dec[l] * B[l][n]  (from registers; dec is per-thread const)
  float decv = sDec[lane];
  #pragma unroll
  for (int k = 0; k < 2; k++) {
    int c8 = w * 16 + 8 * k;
    #pragma unroll
    for (int j = 0; j < 8; j++)
      *(__bf16*)swaddr(smBd, c8 + j, lane) = (__bf16)((float)bch[k][j] * decv);
  }

  int lr = lane & 15, kb = (lane >> 4) * 8;
  int rl = 16 * w + (lane >> 4) * 4;     // acc row base for this wave's strip

  // G = tril(C @ B^T) * exp(Acs[l]-Acs[s]); wave w owns rows 16w..16w+15
  {
    bf16x8 af[2];
    #pragma unroll
    for (int ks = 0; ks < 2; ks++)
      af[ks] = *(const bf16x8*)swaddr(smC, 16 * w + lr, ks * 32 + kb);
    f32x4 g[4] = {};
    #pragma unroll
    for (int nt = 0; nt < 4; nt++)
      #pragma unroll
      for (int ks = 0; ks < 2; ks++) {
        bf16x8 bm = *(const bf16x8*)swaddr(smB, 16 * nt + lr, ks * 32 + kb);
        g[nt] = __builtin_amdgcn_mfma_f32_16x16x32_bf16(af[ks], bm, g[nt], 0, 0, 0);
      }
    #pragma unroll
    for (int nt = 0; nt < 4; nt++)
      #pragma unroll
      for (int q = 0; q < 4; q++) {
        int gl = rl + q, gs = 16 * nt + lr;
        float val = (gl >= gs) ? g[nt][q] * __expf(sAcs[gl] - sAcs[gs]) : 0.f;
        *(__bf16*)swaddr(smG, gl, gs) = (__bf16)val;
      }
  }
  __syncthreads();

  // Y_diag = Gs @ XT^T  (M=l strip 16w, N=p 8 tiles, K=s 2 steps)
  {
    bf16x8 af[2];
    #pragma unroll
    for (int ks = 0; ks < 2; ks++)
      af[ks] = *(const bf16x8*)swaddr(smG, 16 * w + lr, ks * 32 + kb);
    f32x4 y[8] = {};
    #pragma unroll
    for (int nt = 0; nt < 8; nt++)
      #pragma unroll
      for (int ks = 0; ks < 2; ks++) {
        bf16x8 bm = *(const bf16x8*)swaddr(smX, 16 * nt + lr, ks * 32 + kb);
        y[nt] = __builtin_amdgcn_mfma_f32_16x16x32_bf16(af[ks], bm, y[nt], 0, 0, 0);
      }
    #pragma unroll
    for (int nt = 0; nt < 8; nt++)
      #pragma unroll
      for (int q = 0; q < 4; q++)
        Y[(size_t)(row0 + rl + q) * DINNER + h * HEADDIM + 16 * nt + lr] = y[nt][q];
  }

  // S = XT @ BdT^T  (M=p: wave w owns tiles 2w,2w+1; N=n 4 tiles; K=l 2 steps)
  {
    bf16x8 bfs[4][2];
    #pragma unroll
    for (int nt = 0; nt < 4; nt++)
      #pragma unroll
      for (int ks = 0; ks < 2; ks++)
        bfs[nt][ks] = *(const bf16x8*)swaddr(smBd, 16 * nt + lr, ks * 32 + kb);
    f32x4 s4[2][4] = {};
    #pragma unroll
    for (int mi = 0; mi < 2; mi++) {
      bf16x8 af[2];
      #pragma unroll
      for (int ks = 0; ks < 2; ks++)
        af[ks] = *(const bf16x8*)swaddr(smX, 32 * w + 16 * mi + lr, ks * 32 + kb);
      #pragma unroll
      for (int nt = 0; nt < 4; nt++)
        #pragma unroll
        for (int ks = 0; ks < 2; ks++)
          s4[mi][nt] = __builtin_amdgcn_mfma_f32_16x16x32_bf16(af[ks], bfs[nt][ks], s4[mi][nt], 0, 0, 0);
    }
    __bf16* Sp = S + (((size_t)b * NCHUNK + c) * NHEADS + h) * (HEADDIM * DSTATE);
    #pragma unroll
    for (int mi = 0; mi < 2; mi++)
      #pragma unroll
      for (int nt = 0; nt < 4; nt++)
        #pragma unroll
        for (int q = 0; q < 4; q++) {
          int p = 32 * w + 16 * mi + (lane >> 4) * 4 + q;
          Sp[p * DSTATE + 16 * nt + lr] = (__bf16)s4[mi][nt][q];
        }
  }
}

// ---- K6: inter-chunk scan, in-place S -> prev_states ----
__global__ __launch_bounds__(256) void scan_kernel(
    __bf16* SP, const float* __restrict__ ecs)
{
  int t = blockIdx.x * 256 + threadIdx.x;       // 524288 = B*H*P*N
  int n = t & 63, p = (t >> 6) & 127, h = (t >> 13) & 15, b = t >> 17;
  float P = 0.f;
  for (int c = 0; c < NCHUNK; c++) {
    size_t idx = (((size_t)b * NCHUNK + c) * NHEADS + h) * (HEADDIM * DSTATE) + (size_t)p * DSTATE + n;
    float s = (float)SP[idx];
    SP[idx] = (__bf16)P;
    float e = ecs[((size_t)b * NHEADS + h) * NCHUNK + c];
    P = e * P + s;
  }
}

// ---- K7 (MFMA): Y += exp(Acs[l]) * (C @ P^T) + D * x ----
__global__ __launch_bounds__(256) void ssd_off_kernel(
    const __bf16* __restrict__ conv, const __bf16* __restrict__ P,
    const float* __restrict__ acs, const float* __restrict__ Dp,
    float* __restrict__ Y)
{
  __shared__ __align__(16) char sm[24832];
  char* smC = sm;              // [64][64] swz
  char* smP = sm + 8192;       // [128][64] swz
  float* eA = (float*)(sm + 24576);
  int bx = blockIdx.x;
  int c = bx & 31, h = (bx >> 5) & 15, b = bx >> 9;
  int t = threadIdx.x;
  int lane = t & 63, w = t >> 6;
  int row0 = b * LL + c * 64;
  // C: coalesced global b128 + conflict-free swz writes
  #pragma unroll
  for (int k = 0; k < 2; k++) {
    int q = t + 256 * k;
    int lq = q >> 3, c8 = (q & 7) * 8;
    bf16x8 v = *(const bf16x8*)(conv + (size_t)(row0 + lq) * CONVDIM + DINNER + DSTATE + c8);
    *(bf16x8*)swaddr(smC, lq, c8) = v;
  }
  const __bf16* Pp = P + (((size_t)b * NCHUNK + c) * NHEADS + h) * (HEADDIM * DSTATE);
  #pragma unroll
  for (int k = 0; k < 4; k++) {
    int q = t + 256 * k;
    int pr = q >> 3, c8 = (q & 7) * 8;
    bf16x8 v = *(const bf16x8*)(Pp + pr * DSTATE + c8);
    *(bf16x8*)swaddr(smP, pr, c8) = v;
  }
  if (t < 64) eA[t] = __expf(acs[(((size_t)b * NHEADS + h) * NCHUNK + c) * 64 + t]);
  __syncthreads();
  int lr = lane & 15, kb = (lane >> 4) * 8;
  bf16x8 af[2];
  #pragma unroll
  for (int ks = 0; ks < 2; ks++)
    af[ks] = *(const bf16x8*)swaddr(smC, 16 * w + lr, ks * 32 + kb);
  f32x4 y[8] = {};
  #pragma unroll
  for (int nt = 0; nt < 8; nt++)
    #pragma unroll
    for (int ks = 0; ks < 2; ks++) {
      bf16x8 bm = *(const bf16x8*)swaddr(smP, 16 * nt + lr, ks * 32 + kb);
      y[nt] = __builtin_amdgcn_mfma_f32_16x16x32_bf16(af[ks], bm, y[nt], 0, 0, 0);
    }
  float Dh = Dp[h];
  int rl = 16 * w + (lane >> 4) * 4;
  #pragma unroll
  for (int nt = 0; nt < 8; nt++)
    #pragma unroll
    for (int q = 0; q < 4; q++) {
      int l = rl + q;
      int p = 16 * nt + lr;
      size_t yi = (size_t)(row0 + l) * DINNER + h * HEADDIM + p;
      float xsv = (float)conv[(size_t)(row0 + l) * CONVDIM + h * HEADDIM + p];
      Y[yi] += eA[l] * y[nt][q] + Dh * xsv;
    }
}

// ---- K8: y *= silu(z); RMSNorm; -> bf16 ----
__global__ __launch_bounds__(256) void gate_norm_kernel(
    const float* __restrict__ Y, const __bf16* __restrict__ Z,
    const float* __restrict__ rms_w, __bf16* __restrict__ ybf)
{
  int row = blockIdx.x, t = threadIdx.x;
  float v[8]; float ss = 0.f;
  #pragma unroll
  for (int j = 0; j < 8; j++) {
    int i = t + j * 256;
    float zv = (float)Z[(size_t)row * NPAD + i];
    float yv = Y[(size_t)row * DINNER + i];
    float g = yv * (zv / (1.f + __expf(-zv)));
    v[j] = g; ss += g * g;
  }
  #pragma unroll
  for (int m = 32; m; m >>= 1) ss += __shfl_xor(ss, m);
  __shared__ float red[4];
  if ((t & 63) == 0) red[t >> 6] = ss;
  __syncthreads();
  float tot = red[0] + red[1] + red[2] + red[3];
  float r = rsqrtf(tot * (1.f / DINNER) + 1e-5f);
  #pragma unroll
  for (int j = 0; j < 8; j++) {
    int i = t + j * 256;
    ybf[(size_t)row * DINNER + i] = (__bf16)(v[j] * r * rms_w[i]);
  }
}

extern "C" void kernel_launch(void* const* d_in, const int* in_sizes, int n_in,
                              void* d_out, int out_size, void* d_ws, size_t ws_size,
                              hipStream_t stream) {
  const float* x       = (const float*)d_in[0];
  const float* w_embed = (const float*)d_in[1];
  const float* ln_g    = (const float*)d_in[2];
  const float* ln_b    = (const float*)d_in[3];
  const float* W_in    = (const float*)d_in[4];
  const float* conv_w  = (const float*)d_in[5];
  const float* conv_b  = (const float*)d_in[6];
  const float* dt_bias = (const float*)d_in[7];
  const float* A_log   = (const float*)d_in[8];
  const float* Dp      = (const float*)d_in[9];
  const float* rms_w   = (const float*)d_in[10];
  const float* W_out   = (const float*)d_in[11];
  char* ws = (char*)d_ws;
  float*  h32  = (float*)(ws + OF_H32);
  __bf16* hbf  = (__bf16*)(ws + OF_HBF);
  __bf16* Wib  = (__bf16*)(ws + OF_WI);
  __bf16* Wob  = (__bf16*)(ws + OF_WO);
  __bf16* Zbf  = (__bf16*)(ws + OF_Z);
  float*  dtb  = (float*)(ws + OF_DT);
  __bf16* convb = (__bf16*)(ws + OF_CONV);
  __bf16* SP   = (__bf16*)(ws + OF_SP);
  float*  acs  = (float*)(ws + OF_ACS);
  float*  ecs  = (float*)(ws + OF_ECS);
  float*  Y    = (float*)(ws + OF_Y);
  __bf16* ybf  = (__bf16*)(ws + OF_YBF);
  float*  out  = (float*)d_out;

  convert_w_kernel<<<2048, 256, 0, stream>>>(W_in, W_out, Wib, Wob);
  embed_ln_kernel<<<ROWS, 256, 0, stream>>>(x, w_embed, ln_g, ln_b, h32, hbf);
  gemm_bt_kernel<__bf16><<<dim3(NPAD / 128, ROWS / 128), 256, 0, stream>>>(hbf, Wib, Zbf, DMODEL, NPAD);
  dt_kernel<<<ROWS, 256, 0, stream>>>(h32, W_in, dt_bias, dtb);
  conv_kernel<<<(ROWS * CONVDIM) / 256, 256, 0, stream>>>(Zbf, conv_w, conv_b, convb);
  ssd_chunk_kernel<<<BB * NHEADS * NCHUNK, 256, 0, stream>>>(convb, dtb, A_log, Y, SP, acs, ecs);
  scan_kernel<<<(BB * NHEADS * HEADDIM * DSTATE) / 256, 256, 0, stream>>>(SP, ecs);
  ssd_off_kernel<<<BB * NHEADS * NCHUNK, 256, 0, stream>>>(convb, SP, acs, Dp, Y);
  gate_norm_kernel<<<ROWS, 256, 0, stream>>>(Y, Zbf, rms_w, ybf);
  gemm_bt_kernel<float><<<dim3(DMODEL / 128, ROWS / 128), 256, 0, stream>>>(ybf, Wob, out, DINNER, DMODEL);
}

// Round 4
// 439.550 us; speedup vs baseline: 1.2894x; 1.0991x over previous
//
#include <hip/hip_runtime.h>

#define DEV __device__ __forceinline__

typedef __bf16 bf16x8 __attribute__((ext_vector_type(8)));
typedef float f32x4 __attribute__((ext_vector_type(4)));

// ---- constants ----
#define BB 4
#define LL 2048
#define DMODEL 1024
#define DINNER 2048
#define NHEADS 16
#define HEADDIM 128
#define DSTATE 64
#define CONVDIM 2176
#define DINPROJ 4240
#define NPAD 4352
#define NCHUNK 32
#define ROWS (BB*LL)   // 8192

// ---- workspace offsets (bytes) ----
#define OF_H32 ((size_t)0)
#define OF_HBF ((size_t)33554432)
#define OF_WI  ((size_t)50331648)
#define OF_Y   ((size_t)0)
#define OF_WO  ((size_t)67108864)
#define OF_Z   ((size_t)71303168)
#define OF_DT  ((size_t)142606336)
#define OF_CONV ((size_t)143130624)
#define OF_YBF  OF_CONV
#define OF_SP  ((size_t)178782208)
#define OF_ACS ((size_t)212336640)
#define OF_ECS ((size_t)212860928)

DEV void gload_lds16(const void* g, void* l) {
  __builtin_amdgcn_global_load_lds((const __attribute__((address_space(1))) void*)g,
                                   (__attribute__((address_space(3))) void*)l, 16, 0, 0);
}

// XOR-swizzled byte address within a [R][64] bf16 tile (rows = 128 B).
DEV char* swaddr(char* base, int r, int c) {
  return base + r * 128 + (((c) * 2) ^ (((r) & 7) << 4));
}

// ---- K0: weight conversion fp32 -> bf16 ----
__global__ __launch_bounds__(256) void convert_w_kernel(
    const float* __restrict__ Wi, const float* __restrict__ Wo,
    __bf16* __restrict__ Wib, __bf16* __restrict__ Wob)
{
  const int NI = NPAD * DMODEL;
  const int NIr = DINPROJ * DMODEL;
  const int NO = DMODEL * DINNER;
  for (int i = blockIdx.x * 256 + threadIdx.x; i < NI + NO; i += gridDim.x * 256) {
    if (i < NI) Wib[i] = (i < NIr) ? (__bf16)Wi[i] : (__bf16)0.f;
    else        Wob[i - NI] = (__bf16)Wo[i - NI];
  }
}

// ---- K1: embed + layernorm -> h (f32 + bf16) ----
__global__ __launch_bounds__(256) void embed_ln_kernel(
    const float* __restrict__ x, const float* __restrict__ w,
    const float* __restrict__ g, const float* __restrict__ bta,
    float* __restrict__ h32, __bf16* __restrict__ hbf)
{
  int row = blockIdx.x, t = threadIdx.x;
  float xv = x[row];
  float v[4]; float s = 0.f, s2 = 0.f;
  #pragma unroll
  for (int j = 0; j < 4; j++) {
    int i = t + j * 256;
    float hv = xv * w[i];
    v[j] = hv; s += hv; s2 += hv * hv;
  }
  #pragma unroll
  for (int m = 32; m; m >>= 1) { s += __shfl_xor(s, m); s2 += __shfl_xor(s2, m); }
  __shared__ float rs[4], rs2[4];
  if ((t & 63) == 0) { rs[t >> 6] = s; rs2[t >> 6] = s2; }
  __syncthreads();
  s = rs[0] + rs[1] + rs[2] + rs[3];
  s2 = rs2[0] + rs2[1] + rs2[2] + rs2[3];
  float mu = s * (1.f / DMODEL);
  float var = s2 * (1.f / DMODEL) - mu * mu;
  float r = rsqrtf(var + 1e-5f);
  #pragma unroll
  for (int j = 0; j < 4; j++) {
    int i = t + j * 256;
    float o = (v[j] - mu) * r * g[i] + bta[i];
    h32[(size_t)row * DMODEL + i] = o;
    hbf[(size_t)row * DMODEL + i] = (__bf16)o;
  }
}

// ---- K2: 256^2-tile deep-pipelined bf16 GEMM (in_proj) ----
// C[M,N] = A[M,K] @ Bt[N,K]^T. 512 thr / 8 waves (2x4), BK=32, 4-slot LDS ring,
// counted vmcnt (T3+T4), swizzled LDS (T2), setprio (T5), XCD swizzle (T1).
// Requires: M%256==0, N%256==0, K%32==0, K/32>=4, grid%8==0. Dyn LDS 128 KiB.
__global__ __launch_bounds__(512, 2) void gemm256_bt_kernel(
    const __bf16* __restrict__ A, const __bf16* __restrict__ Bt,
    __bf16* __restrict__ C, int K, int N, int nbn)
{
  extern __shared__ char sm[];          // A: 4 x 16KB @0, B: 4 x 16KB @65536
  const int t = threadIdx.x;
  const int lane = t & 63, w = t >> 6;
  const int wr = w >> 2, wc = w & 3;

  // T1: XCD-aware block swizzle (gridDim.x % 8 == 0)
  int nwg = gridDim.x;
  int wg = ((int)blockIdx.x & 7) * (nwg >> 3) + ((int)blockIdx.x >> 3);
  int bm = wg / nbn, bn = wg % nbn;
  int m0 = bm * 256, n0 = bn * 256;

  // staging source decode: linear LDS byte y -> logical (row r, k-byte cb)
  // swizzle: y = pg*128 + (((r&1)<<6 | cb) ^ ((pg&7)<<4)), pg = r>>1 (involution)
  int r0, c0, r1, c1;
  {
    int y0 = t * 16, pg0 = y0 >> 7;
    int in0 = (y0 & 127) ^ ((pg0 & 7) << 4);
    r0 = pg0 * 2 + (in0 >> 6); c0 = in0 & 63;
    int y1 = 8192 + t * 16, pg1 = y1 >> 7;
    int in1 = (y1 & 127) ^ ((pg1 & 7) << 4);
    r1 = pg1 * 2 + (in1 >> 6); c1 = in1 & 63;
  }
  const char* pA0 = (const char*)A + (size_t)(m0 + r0) * (2 * K) + c0;
  const char* pA1 = (const char*)A + (size_t)(m0 + r1) * (2 * K) + c1;
  const char* pB0 = (const char*)Bt + (size_t)(n0 + r0) * (2 * K) + c0;
  const char* pB1 = (const char*)Bt + (size_t)(n0 + r1) * (2 * K) + c1;

  // fragment read offsets (swizzled)
  const int lr = lane & 15, kg = lane >> 4;
  int rA = wr * 128 + lr, pgA = rA >> 1;
  const int offA = pgA * 128 + ((((rA & 1) << 6) | (kg << 4)) ^ ((pgA & 7) << 4));
  int rB = wc * 64 + lr, pgB = rB >> 1;
  const int offB = pgB * 128 + ((((rB & 1) << 6) | (kg << 4)) ^ ((pgB & 7) << 4));

  f32x4 acc[8][4] = {};
  const int KT = K >> 5;

  #define STAGE256(slot) do { \
    char* la_ = sm + (slot) * 16384; \
    char* lb_ = sm + 65536 + (slot) * 16384; \
    gload_lds16(pA0, la_ + t * 16); \
    gload_lds16(pA1, la_ + 8192 + t * 16); \
    gload_lds16(pB0, lb_ + t * 16); \
    gload_lds16(pB1, lb_ + 8192 + t * 16); \
    pA0 += 64; pA1 += 64; pB0 += 64; pB1 += 64; \
  } while (0)

  STAGE256(0); STAGE256(1); STAGE256(2);
  asm volatile("s_waitcnt vmcnt(8)" ::: "memory");
  __builtin_amdgcn_sched_barrier(0);
  __builtin_amdgcn_s_barrier();
  __builtin_amdgcn_sched_barrier(0);

  for (int kt = 0; kt < KT; ++kt) {
    int s = kt & 3;
    if (kt + 3 < KT) STAGE256((kt + 3) & 3);
    const char* sa = sm + s * 16384;
    const char* sb = sm + 65536 + s * 16384;
    bf16x8 af[8], bf[4];
    #pragma unroll
    for (int m = 0; m < 8; m++) af[m] = *(const bf16x8*)(sa + offA + m * 1024);
    #pragma unroll
    for (int n = 0; n < 4; n++) bf[n] = *(const bf16x8*)(sb + offB + n * 1024);
    __builtin_amdgcn_s_setprio(1);
    #pragma unroll
    for (int m = 0; m < 8; m++)
      #pragma unroll
      for (int n = 0; n < 4; n++)
        acc[m][n] = __builtin_amdgcn_mfma_f32_16x16x32_bf16(af[m], bf[n], acc[m][n], 0, 0, 0);
    __builtin_amdgcn_s_setprio(0);
    if (kt + 3 < KT)      { asm volatile("s_waitcnt vmcnt(8)" ::: "memory"); }
    else if (kt + 2 < KT) { asm volatile("s_waitcnt vmcnt(4)" ::: "memory"); }
    else if (kt + 1 < KT) { asm volatile("s_waitcnt vmcnt(0)" ::: "memory"); }
    __builtin_amdgcn_sched_barrier(0);
    __builtin_amdgcn_s_barrier();
    __builtin_amdgcn_sched_barrier(0);
  }
  #undef STAGE256

  // epilogue: C[row, col], row = m0+wr*128+m*16+kg*4+q, col = n0+wc*64+n*16+lr
  #pragma unroll
  for (int m = 0; m < 8; m++) {
    #pragma unroll
    for (int n = 0; n < 4; n++) {
      #pragma unroll
      for (int q = 0; q < 4; q++) {
        int row = m0 + wr * 128 + m * 16 + kg * 4 + q;
        int col = n0 + wc * 64 + n * 16 + lr;
        C[(size_t)row * N + col] = (__bf16)acc[m][n][q];
      }
    }
  }
}

// ---- K9: 128^2 m97-structure GEMM (out_proj) + XCD swizzle ----
template <typename OutT>
__global__ __launch_bounds__(256) void gemm_bt_kernel(
    const __bf16* __restrict__ A, const __bf16* __restrict__ Bt,
    OutT* __restrict__ C, int K, int ldc)
{
  __shared__ __bf16 As[128 * 32];
  __shared__ __bf16 Bs[128 * 32];
  int t = threadIdx.x;
  int lane = t & 63, wave = t >> 6;
  int nbx = gridDim.x;
  int nwg = nbx * gridDim.y;
  int lid = blockIdx.y * nbx + blockIdx.x;
  int wg = (nwg & 7) == 0 ? ((lid & 7) * (nwg >> 3) + (lid >> 3)) : lid;
  int m0 = (wg / nbx) * 128, n0 = (wg % nbx) * 128;
  int wm = (wave >> 1) * 64, wn = (wave & 1) * 64;
  f32x4 acc[4][4] = {};
  int sr = t >> 2;
  int sc = (t & 3) << 3;
  const __bf16* aS = A + (size_t)(m0 + sr) * K + sc;
  const __bf16* bS = Bt + (size_t)(n0 + sr) * K + sc;
  int lr = lane & 15;
  int kb = (lane >> 4) << 3;
  const __bf16* Ap = &As[0] + (wm + lr) * 32 + kb;
  const __bf16* Bp = &Bs[0] + (wn + lr) * 32 + kb;
  for (int k0 = 0; k0 < K; k0 += 32) {
    gload_lds16(aS + k0, &As[8 * t]);
    gload_lds16(aS + (size_t)64 * K + k0, &As[2048 + 8 * t]);
    gload_lds16(bS + k0, &Bs[8 * t]);
    gload_lds16(bS + (size_t)64 * K + k0, &Bs[2048 + 8 * t]);
    __syncthreads();
    bf16x8 af[4], bfr[4];
    #pragma unroll
    for (int i = 0; i < 4; i++) af[i] = *(const bf16x8*)(Ap + i * 16 * 32);
    #pragma unroll
    for (int j = 0; j < 4; j++) bfr[j] = *(const bf16x8*)(Bp + j * 16 * 32);
    #pragma unroll
    for (int i = 0; i < 4; i++)
      #pragma unroll
      for (int j = 0; j < 4; j++)
        acc[i][j] = __builtin_amdgcn_mfma_f32_16x16x32_bf16(af[i], bfr[j], acc[i][j], 0, 0, 0);
    __syncthreads();
  }
  int orow = m0 + wm + (lane >> 4) * 4;
  int ocol = n0 + wn + (lane & 15);
  #pragma unroll
  for (int i = 0; i < 4; i++)
    #pragma unroll
    for (int j = 0; j < 4; j++)
      #pragma unroll
      for (int q = 0; q < 4; q++)
        C[(size_t)(orow + i * 16 + q) * ldc + ocol + j * 16] = (OutT)acc[i][j][q];
}

// ---- K3: fp32 dt recompute + softplus ----
__global__ __launch_bounds__(256) void dt_kernel(
    const float* __restrict__ h32, const float* __restrict__ W_in,
    const float* __restrict__ dt_bias, float* __restrict__ dtb)
{
  int row = blockIdx.x, t = threadIdx.x;
  __shared__ float hs[DMODEL];
  #pragma unroll
  for (int j = 0; j < 4; j++) hs[t + j * 256] = h32[(size_t)row * DMODEL + t + j * 256];
  __syncthreads();
  int head = t >> 4, l16 = t & 15;
  const float* wr = W_in + (size_t)(DINNER + CONVDIM + head) * DMODEL;
  float acc = 0.f;
  #pragma unroll 4
  for (int j = 0; j < 64; j++) {
    int k = j * 16 + l16;
    acc += hs[k] * wr[k];
  }
  #pragma unroll
  for (int m = 8; m; m >>= 1) acc += __shfl_xor(acc, m, 16);
  if (l16 == 0) {
    float vx = acc + dt_bias[head];
    float dt = vx > 15.f ? vx : log1pf(__expf(vx));
    dtb[(size_t)row * NHEADS + head] = dt;
  }
}

// ---- K4: causal depthwise conv1d + silu (vectorized, 8 ch/thread) ----
__global__ __launch_bounds__(256) void conv_kernel(
    const __bf16* __restrict__ Z, const float* __restrict__ conv_w,
    const float* __restrict__ conv_b, __bf16* __restrict__ out)
{
  int g = blockIdx.x * 256 + threadIdx.x;     // ROWS * 272 threads
  if (g >= ROWS * (CONVDIM / 8)) return;
  int cg = g % (CONVDIM / 8);
  int row = g / (CONVDIM / 8);
  int l = row & (LL - 1), b = row >> 11;
  int ch = cg * 8;
  float acc[8]; f32x4 wv[8];
  #pragma unroll
  for (int j = 0; j < 8; j++) {
    acc[j] = conv_b[ch + j];
    wv[j] = *(const f32x4*)(conv_w + (ch + j) * 4);
  }
  #pragma unroll
  for (int k = 0; k < 4; k++) {
    int li = l + k - 3;
    if (li >= 0) {
      bf16x8 v = *(const bf16x8*)(Z + (size_t)(b * LL + li) * NPAD + DINNER + ch);
      #pragma unroll
      for (int j = 0; j < 8; j++) acc[j] += (float)v[j] * wv[j][k];
    }
  }
  bf16x8 o;
  #pragma unroll
  for (int j = 0; j < 8; j++) {
    float s = acc[j] / (1.f + __expf(-acc[j]));
    o[j] = (__bf16)s;
  }
  *(bf16x8*)(out + (size_t)row * CONVDIM + ch) = o;
}

// ---- K5: per-chunk intra (MFMA): Acs, G, Y_diag, chunk states ----
__global__ __launch_bounds__(256) void ssd_chunk_kernel(
    const __bf16* __restrict__ conv, const float* __restrict__ dtb,
    const float* __restrict__ A_log, float* __restrict__ Y,
    __bf16* __restrict__ S, float* __restrict__ acs, float* __restrict__ ecs)
{
  __shared__ __align__(16) char sm[49664];
  char* smC  = sm;
  char* smB  = sm + 8192;
  char* smBd = sm + 16384;
  char* smG  = sm + 24576;
  char* smX  = sm + 32768;
  float* sAcs = (float*)(sm + 49152);
  float* sDec = (float*)(sm + 49408);

  int bx = blockIdx.x;
  int c = bx & 31, h = (bx >> 5) & 15, b = bx >> 9;
  int t = threadIdx.x;
  int lane = t & 63, w = t >> 6;
  int row0 = b * LL + c * 64;
  const __bf16* cr = conv + (size_t)(row0 + lane) * CONVDIM;
  float dtv = dtb[(size_t)(row0 + lane) * NHEADS + h];

  bf16x8 bch[2], cch[2], xch[4];
  #pragma unroll
  for (int k = 0; k < 2; k++) {
    int c8 = w * 16 + 8 * k;
    bch[k] = *(const bf16x8*)(cr + DINNER + c8);
    cch[k] = *(const bf16x8*)(cr + DINNER + DSTATE + c8);
  }
  #pragma unroll
  for (int k = 0; k < 4; k++)
    xch[k] = *(const bf16x8*)(cr + h * HEADDIM + w * 8 + 32 * k);

  if (t < 64) {
    float Ah = -__expf(A_log[h]);
    float cs = dtv * Ah;
    #pragma unroll
    for (int off = 1; off < 64; off <<= 1) {
      float o = __shfl_up(cs, off);
      if (lane >= off) cs += o;
    }
    float cend = __shfl(cs, 63);
    sAcs[lane] = cs;
    sDec[lane] = __expf(cend - cs);
    acs[(((size_t)b * NHEADS + h) * NCHUNK + c) * 64 + lane] = cs;
    if (lane == 63) ecs[((size_t)b * NHEADS + h) * NCHUNK + c] = __expf(cend);
  }

  #pragma unroll
  for (int k = 0; k < 2; k++) {
    int c8 = w * 16 + 8 * k;
    *(bf16x8*)swaddr(smB, lane, c8) = bch[k];
    *(bf16x8*)swaddr(smC, lane, c8) = cch[k];
  }
  #pragma unroll
  for (int k = 0; k < 4; k++) {
    int p0 = w * 8 + 32 * k;
    #pragma unroll
    for (int j = 0; j < 8; j++)
      *(__bf16*)swaddr(smX, p0 + j, lane) = (__bf16)((float)xch[k][j] * dtv);
  }
  __syncthreads();

  float decv = sDec[lane];
  #pragma unroll
  for (int k = 0; k < 2; k++) {
    int c8 = w * 16 + 8 * k;
    #pragma unroll
    for (int j = 0; j < 8; j++)
      *(__bf16*)swaddr(smBd, c8 + j, lane) = (__bf16)((float)bch[k][j] * decv);
  }

  int lr = lane & 15, kb = (lane >> 4) * 8;
  int rl = 16 * w + (lane >> 4) * 4;

  {
    bf16x8 af[2];
    #pragma unroll
    for (int ks = 0; ks < 2; ks++)
      af[ks] = *(const bf16x8*)swaddr(smC, 16 * w + lr, ks * 32 + kb);
    f32x4 g[4] = {};
    #pragma unroll
    for (int nt = 0; nt < 4; nt++)
      #pragma unroll
      for (int ks = 0; ks < 2; ks++) {
        bf16x8 bm = *(const bf16x8*)swaddr(smB, 16 * nt + lr, ks * 32 + kb);
        g[nt] = __builtin_amdgcn_mfma_f32_16x16x32_bf16(af[ks], bm, g[nt], 0, 0, 0);
      }
    #pragma unroll
    for (int nt = 0; nt < 4; nt++)
      #pragma unroll
      for (int q = 0; q < 4; q++) {
        int gl = rl + q, gs = 16 * nt + lr;
        float val = (gl >= gs) ? g[nt][q] * __expf(sAcs[gl] - sAcs[gs]) : 0.f;
        *(__bf16*)swaddr(smG, gl, gs) = (__bf16)val;
      }
  }
  __syncthreads();

  {
    bf16x8 af[2];
    #pragma unroll
    for (int ks = 0; ks < 2; ks++)
      af[ks] = *(const bf16x8*)swaddr(smG, 16 * w + lr, ks * 32 + kb);
    f32x4 y[8] = {};
    #pragma unroll
    for (int nt = 0; nt < 8; nt++)
      #pragma unroll
      for (int ks = 0; ks < 2; ks++) {
        bf16x8 bm = *(const bf16x8*)swaddr(smX, 16 * nt + lr, ks * 32 + kb);
        y[nt] = __builtin_amdgcn_mfma_f32_16x16x32_bf16(af[ks], bm, y[nt], 0, 0, 0);
      }
    #pragma unroll
    for (int nt = 0; nt < 8; nt++)
      #pragma unroll
      for (int q = 0; q < 4; q++)
        Y[(size_t)(row0 + rl + q) * DINNER + h * HEADDIM + 16 * nt + lr] = y[nt][q];
  }

  {
    bf16x8 bfs[4][2];
    #pragma unroll
    for (int nt = 0; nt < 4; nt++)
      #pragma unroll
      for (int ks = 0; ks < 2; ks++)
        bfs[nt][ks] = *(const bf16x8*)swaddr(smBd, 16 * nt + lr, ks * 32 + kb);
    f32x4 s4[2][4] = {};
    #pragma unroll
    for (int mi = 0; mi < 2; mi++) {
      bf16x8 af[2];
      #pragma unroll
      for (int ks = 0; ks < 2; ks++)
        af[ks] = *(const bf16x8*)swaddr(smX, 32 * w + 16 * mi + lr, ks * 32 + kb);
      #pragma unroll
      for (int nt = 0; nt < 4; nt++)
        #pragma unroll
        for (int ks = 0; ks < 2; ks++)
          s4[mi][nt] = __builtin_amdgcn_mfma_f32_16x16x32_bf16(af[ks], bfs[nt][ks], s4[mi][nt], 0, 0, 0);
    }
    __bf16* Sp = S + (((size_t)b * NCHUNK + c) * NHEADS + h) * (HEADDIM * DSTATE);
    #pragma unroll
    for (int mi = 0; mi < 2; mi++)
      #pragma unroll
      for (int nt = 0; nt < 4; nt++)
        #pragma unroll
        for (int q = 0; q < 4; q++) {
          int p = 32 * w + 16 * mi + (lane >> 4) * 4 + q;
          Sp[p * DSTATE + 16 * nt + lr] = (__bf16)s4[mi][nt][q];
        }
  }
}

// ---- K6: inter-chunk scan, in-place S -> prev_states ----
__global__ __launch_bounds__(256) void scan_kernel(
    __bf16* SP, const float* __restrict__ ecs)
{
  int t = blockIdx.x * 256 + threadIdx.x;
  int n = t & 63, p = (t >> 6) & 127, h = (t >> 13) & 15, b = t >> 17;
  float P = 0.f;
  for (int c = 0; c < NCHUNK; c++) {
    size_t idx = (((size_t)b * NCHUNK + c) * NHEADS + h) * (HEADDIM * DSTATE) + (size_t)p * DSTATE + n;
    float s = (float)SP[idx];
    SP[idx] = (__bf16)P;
    float e = ecs[((size_t)b * NHEADS + h) * NCHUNK + c];
    P = e * P + s;
  }
}

// ---- K7 (MFMA): Y += exp(Acs[l]) * (C @ P^T) + D * x ----
__global__ __launch_bounds__(256) void ssd_off_kernel(
    const __bf16* __restrict__ conv, const __bf16* __restrict__ P,
    const float* __restrict__ acs, const float* __restrict__ Dp,
    float* __restrict__ Y)
{
  __shared__ __align__(16) char sm[24832];
  char* smC = sm;
  char* smP = sm + 8192;
  float* eA = (float*)(sm + 24576);
  int bx = blockIdx.x;
  int c = bx & 31, h = (bx >> 5) & 15, b = bx >> 9;
  int t = threadIdx.x;
  int lane = t & 63, w = t >> 6;
  int row0 = b * LL + c * 64;
  #pragma unroll
  for (int k = 0; k < 2; k++) {
    int q = t + 256 * k;
    int lq = q >> 3, c8 = (q & 7) * 8;
    bf16x8 v = *(const bf16x8*)(conv + (size_t)(row0 + lq) * CONVDIM + DINNER + DSTATE + c8);
    *(bf16x8*)swaddr(smC, lq, c8) = v;
  }
  const __bf16* Pp = P + (((size_t)b * NCHUNK + c) * NHEADS + h) * (HEADDIM * DSTATE);
  #pragma unroll
  for (int k = 0; k < 4; k++) {
    int q = t + 256 * k;
    int pr = q >> 3, c8 = (q & 7) * 8;
    bf16x8 v = *(const bf16x8*)(Pp + pr * DSTATE + c8);
    *(bf16x8*)swaddr(smP, pr, c8) = v;
  }
  if (t < 64) eA[t] = __expf(acs[(((size_t)b * NHEADS + h) * NCHUNK + c) * 64 + t]);
  __syncthreads();
  int lr = lane & 15, kb = (lane >> 4) * 8;
  bf16x8 af[2];
  #pragma unroll
  for (int ks = 0; ks < 2; ks++)
    af[ks] = *(const bf16x8*)swaddr(smC, 16 * w + lr, ks * 32 + kb);
  f32x4 y[8] = {};
  #pragma unroll
  for (int nt = 0; nt < 8; nt++)
    #pragma unroll
    for (int ks = 0; ks < 2; ks++) {
      bf16x8 bm = *(const bf16x8*)swaddr(smP, 16 * nt + lr, ks * 32 + kb);
      y[nt] = __builtin_amdgcn_mfma_f32_16x16x32_bf16(af[ks], bm, y[nt], 0, 0, 0);
    }
  float Dh = Dp[h];
  int rl = 16 * w + (lane >> 4) * 4;
  #pragma unroll
  for (int nt = 0; nt < 8; nt++)
    #pragma unroll
    for (int q = 0; q < 4; q++) {
      int l = rl + q;
      int p = 16 * nt + lr;
      size_t yi = (size_t)(row0 + l) * DINNER + h * HEADDIM + p;
      float xsv = (float)conv[(size_t)(row0 + l) * CONVDIM + h * HEADDIM + p];
      Y[yi] += eA[l] * y[nt][q] + Dh * xsv;
    }
}

// ---- K8: y *= silu(z); RMSNorm; -> bf16 ----
__global__ __launch_bounds__(256) void gate_norm_kernel(
    const float* __restrict__ Y, const __bf16* __restrict__ Z,
    const float* __restrict__ rms_w, __bf16* __restrict__ ybf)
{
  int row = blockIdx.x, t = threadIdx.x;
  float v[8]; float ss = 0.f;
  #pragma unroll
  for (int j = 0; j < 8; j++) {
    int i = t + j * 256;
    float zv = (float)Z[(size_t)row * NPAD + i];
    float yv = Y[(size_t)row * DINNER + i];
    float g = yv * (zv / (1.f + __expf(-zv)));
    v[j] = g; ss += g * g;
  }
  #pragma unroll
  for (int m = 32; m; m >>= 1) ss += __shfl_xor(ss, m);
  __shared__ float red[4];
  if ((t & 63) == 0) red[t >> 6] = ss;
  __syncthreads();
  float tot = red[0] + red[1] + red[2] + red[3];
  float r = rsqrtf(tot * (1.f / DINNER) + 1e-5f);
  #pragma unroll
  for (int j = 0; j < 8; j++) {
    int i = t + j * 256;
    ybf[(size_t)row * DINNER + i] = (__bf16)(v[j] * r * rms_w[i]);
  }
}

extern "C" void kernel_launch(void* const* d_in, const int* in_sizes, int n_in,
                              void* d_out, int out_size, void* d_ws, size_t ws_size,
                              hipStream_t stream) {
  const float* x       = (const float*)d_in[0];
  const float* w_embed = (const float*)d_in[1];
  const float* ln_g    = (const float*)d_in[2];
  const float* ln_b    = (const float*)d_in[3];
  const float* W_in    = (const float*)d_in[4];
  const float* conv_w  = (const float*)d_in[5];
  const float* conv_b  = (const float*)d_in[6];
  const float* dt_bias = (const float*)d_in[7];
  const float* A_log   = (const float*)d_in[8];
  const float* Dp      = (const float*)d_in[9];
  const float* rms_w   = (const float*)d_in[10];
  const float* W_out   = (const float*)d_in[11];
  char* ws = (char*)d_ws;
  float*  h32  = (float*)(ws + OF_H32);
  __bf16* hbf  = (__bf16*)(ws + OF_HBF);
  __bf16* Wib  = (__bf16*)(ws + OF_WI);
  __bf16* Wob  = (__bf16*)(ws + OF_WO);
  __bf16* Zbf  = (__bf16*)(ws + OF_Z);
  float*  dtb  = (float*)(ws + OF_DT);
  __bf16* convb = (__bf16*)(ws + OF_CONV);
  __bf16* SP   = (__bf16*)(ws + OF_SP);
  float*  acs  = (float*)(ws + OF_ACS);
  float*  ecs  = (float*)(ws + OF_ECS);
  float*  Y    = (float*)(ws + OF_Y);
  __bf16* ybf  = (__bf16*)(ws + OF_YBF);
  float*  out  = (float*)d_out;

  hipFuncSetAttribute((const void*)gemm256_bt_kernel,
                      hipFuncAttributeMaxDynamicSharedMemorySize, 131072);

  convert_w_kernel<<<2048, 256, 0, stream>>>(W_in, W_out, Wib, Wob);
  embed_ln_kernel<<<ROWS, 256, 0, stream>>>(x, w_embed, ln_g, ln_b, h32, hbf);
  gemm256_bt_kernel<<<(ROWS / 256) * (NPAD / 256), 512, 131072, stream>>>(
      hbf, Wib, Zbf, DMODEL, NPAD, NPAD / 256);
  dt_kernel<<<ROWS, 256, 0, stream>>>(h32, W_in, dt_bias, dtb);
  conv_kernel<<<(ROWS * (CONVDIM / 8) + 255) / 256, 256, 0, stream>>>(Zbf, conv_w, conv_b, convb);
  ssd_chunk_kernel<<<BB * NHEADS * NCHUNK, 256, 0, stream>>>(convb, dtb, A_log, Y, SP, acs, ecs);
  scan_kernel<<<(BB * NHEADS * HEADDIM * DSTATE) / 256, 256, 0, stream>>>(SP, ecs);
  ssd_off_kernel<<<BB * NHEADS * NCHUNK, 256, 0, stream>>>(convb, SP, acs, Dp, Y);
  gate_norm_kernel<<<ROWS, 256, 0, stream>>>(Y, Zbf, rms_w, ybf);
  gemm_bt_kernel<float><<<dim3(DMODEL / 128, ROWS / 128), 256, 0, stream>>>(ybf, Wob, out, DINNER, DMODEL);
}

// Round 6
// 416.852 us; speedup vs baseline: 1.3597x; 1.0544x over previous
//
#include <hip/hip_runtime.h>

#define DEV __device__ __forceinline__

typedef __bf16 bf16x8 __attribute__((ext_vector_type(8)));
typedef float f32x4 __attribute__((ext_vector_type(4)));

// ---- constants ----
#define BB 4
#define LL 2048
#define DMODEL 1024
#define DINNER 2048
#define NHEADS 16
#define HEADDIM 128
#define DSTATE 64
#define CONVDIM 2176
#define DINPROJ 4240
#define NPAD 4352
#define NCHUNK 32
#define ROWS (BB*LL)   // 8192

// ---- workspace offsets (bytes) ----
#define OF_Y   ((size_t)0)                       // 8192*2048*2 = 33554432 (bf16 now)
#define OF_HBF ((size_t)33554432)                // 16777216
#define OF_WI  ((size_t)50331648)                // 8912896
#define OF_WO  ((size_t)67108864)                // 4194304
#define OF_Z   ((size_t)71303168)                // 71303168
#define OF_DT  ((size_t)142606336)               // 524288
#define OF_CONV ((size_t)143130624)              // 35651584
#define OF_YBF  OF_CONV                          // overlays conv (after ssd_off done)
#define OF_SP  ((size_t)178782208)               // 33554432
#define OF_ACS ((size_t)212336640)               // 524288
#define OF_ECS ((size_t)212860928)               // 8192

DEV void gload_lds16(const void* g, void* l) {
  __builtin_amdgcn_global_load_lds((const __attribute__((address_space(1))) void*)g,
                                   (__attribute__((address_space(3))) void*)l, 16, 0, 0);
}

// XOR-swizzled byte address within a [R][64] bf16 tile (rows = 128 B).
DEV char* swaddr(char* base, int r, int c) {
  return base + r * 128 + (((c) * 2) ^ (((r) & 7) << 4));
}

// ---- K0: weight conversion fp32 -> bf16 ----
__global__ __launch_bounds__(256) void convert_w_kernel(
    const float* __restrict__ Wi, const float* __restrict__ Wo,
    __bf16* __restrict__ Wib, __bf16* __restrict__ Wob)
{
  const int NI = NPAD * DMODEL;
  const int NIr = DINPROJ * DMODEL;
  const int NO = DMODEL * DINNER;
  for (int i = blockIdx.x * 256 + threadIdx.x; i < NI + NO; i += gridDim.x * 256) {
    if (i < NI) Wib[i] = (i < NIr) ? (__bf16)Wi[i] : (__bf16)0.f;
    else        Wob[i - NI] = (__bf16)Wo[i - NI];
  }
}

// ---- K1: embed + layernorm -> hbf; fused fp32 dt (softplus) ----
__global__ __launch_bounds__(256) void embed_ln_kernel(
    const float* __restrict__ x, const float* __restrict__ w,
    const float* __restrict__ g, const float* __restrict__ bta,
    const float* __restrict__ W_in, const float* __restrict__ dt_bias,
    __bf16* __restrict__ hbf, float* __restrict__ dtb)
{
  __shared__ float hs[DMODEL];
  int row = blockIdx.x, t = threadIdx.x;
  float xv = x[row];
  float v[4]; float s = 0.f, s2 = 0.f;
  #pragma unroll
  for (int j = 0; j < 4; j++) {
    int i = t + j * 256;
    float hv = xv * w[i];
    v[j] = hv; s += hv; s2 += hv * hv;
  }
  #pragma unroll
  for (int m = 32; m; m >>= 1) { s += __shfl_xor(s, m); s2 += __shfl_xor(s2, m); }
  __shared__ float rs[4], rs2[4];
  if ((t & 63) == 0) { rs[t >> 6] = s; rs2[t >> 6] = s2; }
  __syncthreads();
  s = rs[0] + rs[1] + rs[2] + rs[3];
  s2 = rs2[0] + rs2[1] + rs2[2] + rs2[3];
  float mu = s * (1.f / DMODEL);
  float var = s2 * (1.f / DMODEL) - mu * mu;
  float r = rsqrtf(var + 1e-5f);
  #pragma unroll
  for (int j = 0; j < 4; j++) {
    int i = t + j * 256;
    float o = (v[j] - mu) * r * g[i] + bta[i];
    hs[i] = o;
    hbf[(size_t)row * DMODEL + i] = (__bf16)o;
  }
  __syncthreads();
  // fp32 dt: 16 heads, 16 lanes each
  int head = t >> 4, l16 = t & 15;
  const float* wr_ = W_in + (size_t)(DINNER + CONVDIM + head) * DMODEL;
  float acc = 0.f;
  #pragma unroll 4
  for (int j = 0; j < 64; j++) {
    int k = j * 16 + l16;
    acc += hs[k] * wr_[k];
  }
  #pragma unroll
  for (int m = 8; m; m >>= 1) acc += __shfl_xor(acc, m, 16);
  if (l16 == 0) {
    float vx = acc + dt_bias[head];
    float dt = vx > 15.f ? vx : log1pf(__expf(vx));
    dtb[(size_t)row * NHEADS + head] = dt;
  }
}

// ---- K2: 256^2-tile phase-split bf16 GEMM (in_proj) ----
// 512 thr / 8 waves (2Mx4N), BK=32, 4-slot LDS ring (128 KiB dyn), 2 phases/tile
// each {ds_read || gload -> barrier -> setprio+16 MFMA -> barrier}; vmcnt(8)/tile.
__global__ __launch_bounds__(512, 2) void gemm256_bt_kernel(
    const __bf16* __restrict__ A, const __bf16* __restrict__ Bt,
    __bf16* __restrict__ C, int K, int N, int nbn)
{
  extern __shared__ char sm[];          // A: 4 x 16KB @0, B: 4 x 16KB @65536
  const int t = threadIdx.x;
  const int lane = t & 63, w = t >> 6;
  const int wr = w >> 2, wc = w & 3;

  // T1: XCD-aware block swizzle (grid % 8 == 0)
  int nwg = gridDim.x;
  int wg = ((int)blockIdx.x & 7) * (nwg >> 3) + ((int)blockIdx.x >> 3);
  int bm = wg / nbn, bn = wg % nbn;
  int m0 = bm * 256, n0 = bn * 256;

  // staging source decode (inverse of LDS swizzle; verified conflict-free R4)
  int r0, c0, r1, c1;
  {
    int y0 = t * 16, pg0 = y0 >> 7;
    int in0 = (y0 & 127) ^ ((pg0 & 7) << 4);
    r0 = pg0 * 2 + (in0 >> 6); c0 = in0 & 63;
    int y1 = 8192 + t * 16, pg1 = y1 >> 7;
    int in1 = (y1 & 127) ^ ((pg1 & 7) << 4);
    r1 = pg1 * 2 + (in1 >> 6); c1 = in1 & 63;
  }
  const char* pA0 = (const char*)A + (size_t)(m0 + r0) * (2 * K) + c0;
  const char* pA1 = (const char*)A + (size_t)(m0 + r1) * (2 * K) + c1;
  const char* pB0 = (const char*)Bt + (size_t)(n0 + r0) * (2 * K) + c0;
  const char* pB1 = (const char*)Bt + (size_t)(n0 + r1) * (2 * K) + c1;

  // fragment read offsets (swizzled)
  const int lr = lane & 15, kg = lane >> 4;
  int rA = wr * 128 + lr, pgA = rA >> 1;
  const int offA = pgA * 128 + ((((rA & 1) << 6) | (kg << 4)) ^ ((pgA & 7) << 4));
  int rB = wc * 64 + lr, pgB = rB >> 1;
  const int offB = pgB * 128 + ((((rB & 1) << 6) | (kg << 4)) ^ ((pgB & 7) << 4));

  f32x4 acc[8][4] = {};
  const int KT = K >> 5;

  #define STAGE_A(slot) do { \
    char* la_ = sm + (slot) * 16384; \
    gload_lds16(pA0, la_ + t * 16); \
    gload_lds16(pA1, la_ + 8192 + t * 16); \
    pA0 += 64; pA1 += 64; \
  } while (0)
  #define STAGE_B(slot) do { \
    char* lb_ = sm + 65536 + (slot) * 16384; \
    gload_lds16(pB0, lb_ + t * 16); \
    gload_lds16(pB1, lb_ + 8192 + t * 16); \
    pB0 += 64; pB1 += 64; \
  } while (0)

  STAGE_A(0); STAGE_B(0);
  STAGE_A(1); STAGE_B(1);
  STAGE_A(2); STAGE_B(2);
  asm volatile("s_waitcnt vmcnt(8)" ::: "memory");
  __builtin_amdgcn_sched_barrier(0);
  __builtin_amdgcn_s_barrier();

  for (int kt = 0; kt < KT; ++kt) {
    int s = kt & 3;
    const char* sa = sm + s * 16384;
    const char* sb = sm + 65536 + s * 16384;
    bf16x8 af[4], bf[4];
    // ---- phase 0: frags m0-3 + B, stage A(kt+3) ----
    #pragma unroll
    for (int m = 0; m < 4; m++) af[m] = *(const bf16x8*)(sa + offA + m * 1024);
    #pragma unroll
    for (int n = 0; n < 4; n++) bf[n] = *(const bf16x8*)(sb + offB + n * 1024);
    if (kt + 3 < KT) STAGE_A((kt + 3) & 3);
    __builtin_amdgcn_sched_barrier(0);
    __builtin_amdgcn_s_barrier();
    __builtin_amdgcn_s_setprio(1);
    #pragma unroll
    for (int m = 0; m < 4; m++)
      #pragma unroll
      for (int n = 0; n < 4; n++)
        acc[m][n] = __builtin_amdgcn_mfma_f32_16x16x32_bf16(af[m], bf[n], acc[m][n], 0, 0, 0);
    __builtin_amdgcn_s_setprio(0);
    __builtin_amdgcn_sched_barrier(0);
    __builtin_amdgcn_s_barrier();
    // ---- phase 1: frags m4-7 (B held), stage B(kt+3) ----
    #pragma unroll
    for (int m = 0; m < 4; m++) af[m] = *(const bf16x8*)(sa + offA + (m + 4) * 1024);
    if (kt + 3 < KT) STAGE_B((kt + 3) & 3);
    __builtin_amdgcn_sched_barrier(0);
    __builtin_amdgcn_s_barrier();
    __builtin_amdgcn_s_setprio(1);
    #pragma unroll
    for (int m = 0; m < 4; m++)
      #pragma unroll
      for (int n = 0; n < 4; n++)
        acc[m + 4][n] = __builtin_amdgcn_mfma_f32_16x16x32_bf16(af[m], bf[n], acc[m + 4][n], 0, 0, 0);
    __builtin_amdgcn_s_setprio(0);
    if (kt + 3 < KT)      { asm volatile("s_waitcnt vmcnt(8)" ::: "memory"); }
    else if (kt + 2 < KT) { asm volatile("s_waitcnt vmcnt(4)" ::: "memory"); }
    else if (kt + 1 < KT) { asm volatile("s_waitcnt vmcnt(0)" ::: "memory"); }
    __builtin_amdgcn_sched_barrier(0);
    __builtin_amdgcn_s_barrier();
  }
  #undef STAGE_A
  #undef STAGE_B

  #pragma unroll
  for (int m = 0; m < 8; m++) {
    #pragma unroll
    for (int n = 0; n < 4; n++) {
      #pragma unroll
      for (int q = 0; q < 4; q++) {
        int row = m0 + wr * 128 + m * 16 + kg * 4 + q;
        int col = n0 + wc * 64 + n * 16 + lr;
        C[(size_t)row * N + col] = (__bf16)acc[m][n][q];
      }
    }
  }
}

// ---- K9: 128^2 m97-structure GEMM (out_proj) + XCD swizzle ----
template <typename OutT>
__global__ __launch_bounds__(256) void gemm_bt_kernel(
    const __bf16* __restrict__ A, const __bf16* __restrict__ Bt,
    OutT* __restrict__ C, int K, int ldc)
{
  __shared__ __bf16 As[128 * 32];
  __shared__ __bf16 Bs[128 * 32];
  int t = threadIdx.x;
  int lane = t & 63, wave = t >> 6;
  int nbx = gridDim.x;
  int nwg = nbx * gridDim.y;
  int lid = blockIdx.y * nbx + blockIdx.x;
  int wg = (nwg & 7) == 0 ? ((lid & 7) * (nwg >> 3) + (lid >> 3)) : lid;
  int m0 = (wg / nbx) * 128, n0 = (wg % nbx) * 128;
  int wm = (wave >> 1) * 64, wn = (wave & 1) * 64;
  f32x4 acc[4][4] = {};
  int sr = t >> 2;
  int sc = (t & 3) << 3;
  const __bf16* aS = A + (size_t)(m0 + sr) * K + sc;
  const __bf16* bS = Bt + (size_t)(n0 + sr) * K + sc;
  int lr = lane & 15;
  int kb = (lane >> 4) << 3;
  const __bf16* Ap = &As[0] + (wm + lr) * 32 + kb;
  const __bf16* Bp = &Bs[0] + (wn + lr) * 32 + kb;
  for (int k0 = 0; k0 < K; k0 += 32) {
    gload_lds16(aS + k0, &As[8 * t]);
    gload_lds16(aS + (size_t)64 * K + k0, &As[2048 + 8 * t]);
    gload_lds16(bS + k0, &Bs[8 * t]);
    gload_lds16(bS + (size_t)64 * K + k0, &Bs[2048 + 8 * t]);
    __syncthreads();
    bf16x8 af[4], bfr[4];
    #pragma unroll
    for (int i = 0; i < 4; i++) af[i] = *(const bf16x8*)(Ap + i * 16 * 32);
    #pragma unroll
    for (int j = 0; j < 4; j++) bfr[j] = *(const bf16x8*)(Bp + j * 16 * 32);
    #pragma unroll
    for (int i = 0; i < 4; i++)
      #pragma unroll
      for (int j = 0; j < 4; j++)
        acc[i][j] = __builtin_amdgcn_mfma_f32_16x16x32_bf16(af[i], bfr[j], acc[i][j], 0, 0, 0);
    __syncthreads();
  }
  int orow = m0 + wm + (lane >> 4) * 4;
  int ocol = n0 + wn + (lane & 15);
  #pragma unroll
  for (int i = 0; i < 4; i++)
    #pragma unroll
    for (int j = 0; j < 4; j++)
      #pragma unroll
      for (int q = 0; q < 4; q++)
        C[(size_t)(orow + i * 16 + q) * ldc + ocol + j * 16] = (OutT)acc[i][j][q];
}

// ---- K4: causal depthwise conv1d + silu (vectorized, 8 ch/thread) ----
__global__ __launch_bounds__(256) void conv_kernel(
    const __bf16* __restrict__ Z, const float* __restrict__ conv_w,
    const float* __restrict__ conv_b, __bf16* __restrict__ out)
{
  int g = blockIdx.x * 256 + threadIdx.x;
  if (g >= ROWS * (CONVDIM / 8)) return;
  int cg = g % (CONVDIM / 8);
  int row = g / (CONVDIM / 8);
  int l = row & (LL - 1), b = row >> 11;
  int ch = cg * 8;
  float acc[8]; f32x4 wv[8];
  #pragma unroll
  for (int j = 0; j < 8; j++) {
    acc[j] = conv_b[ch + j];
    wv[j] = *(const f32x4*)(conv_w + (ch + j) * 4);
  }
  #pragma unroll
  for (int k = 0; k < 4; k++) {
    int li = l + k - 3;
    if (li >= 0) {
      bf16x8 v = *(const bf16x8*)(Z + (size_t)(b * LL + li) * NPAD + DINNER + ch);
      #pragma unroll
      for (int j = 0; j < 8; j++) acc[j] += (float)v[j] * wv[j][k];
    }
  }
  bf16x8 o;
  #pragma unroll
  for (int j = 0; j < 8; j++) {
    float s = acc[j] / (1.f + __expf(-acc[j]));
    o[j] = (__bf16)s;
  }
  *(bf16x8*)(out + (size_t)row * CONVDIM + ch) = o;
}

// ---- K5: per-chunk intra (MFMA): Acs, G, Y_diag, chunk states ----
__global__ __launch_bounds__(256) void ssd_chunk_kernel(
    const __bf16* __restrict__ conv, const float* __restrict__ dtb,
    const float* __restrict__ A_log, __bf16* __restrict__ Y,
    __bf16* __restrict__ S, float* __restrict__ acs, float* __restrict__ ecs)
{
  __shared__ __align__(16) char sm[49664];
  char* smC  = sm;
  char* smB  = sm + 8192;
  char* smBd = sm + 16384;
  char* smG  = sm + 24576;
  char* smX  = sm + 32768;
  float* sAcs = (float*)(sm + 49152);
  float* sDec = (float*)(sm + 49408);

  int bx = blockIdx.x;
  int c = bx & 31, h = (bx >> 5) & 15, b = bx >> 9;
  int t = threadIdx.x;
  int lane = t & 63, w = t >> 6;
  int row0 = b * LL + c * 64;
  const __bf16* cr = conv + (size_t)(row0 + lane) * CONVDIM;
  float dtv = dtb[(size_t)(row0 + lane) * NHEADS + h];

  bf16x8 bch[2], cch[2], xch[4];
  #pragma unroll
  for (int k = 0; k < 2; k++) {
    int c8 = w * 16 + 8 * k;
    bch[k] = *(const bf16x8*)(cr + DINNER + c8);
    cch[k] = *(const bf16x8*)(cr + DINNER + DSTATE + c8);
  }
  #pragma unroll
  for (int k = 0; k < 4; k++)
    xch[k] = *(const bf16x8*)(cr + h * HEADDIM + w * 8 + 32 * k);

  if (t < 64) {
    float Ah = -__expf(A_log[h]);
    float cs = dtv * Ah;
    #pragma unroll
    for (int off = 1; off < 64; off <<= 1) {
      float o = __shfl_up(cs, off);
      if (lane >= off) cs += o;
    }
    float cend = __shfl(cs, 63);
    sAcs[lane] = cs;
    sDec[lane] = __expf(cend - cs);
    acs[(((size_t)b * NHEADS + h) * NCHUNK + c) * 64 + lane] = cs;
    if (lane == 63) ecs[((size_t)b * NHEADS + h) * NCHUNK + c] = __expf(cend);
  }

  #pragma unroll
  for (int k = 0; k < 2; k++) {
    int c8 = w * 16 + 8 * k;
    *(bf16x8*)swaddr(smB, lane, c8) = bch[k];
    *(bf16x8*)swaddr(smC, lane, c8) = cch[k];
  }
  #pragma unroll
  for (int k = 0; k < 4; k++) {
    int p0 = w * 8 + 32 * k;
    #pragma unroll
    for (int j = 0; j < 8; j++)
      *(__bf16*)swaddr(smX, p0 + j, lane) = (__bf16)((float)xch[k][j] * dtv);
  }
  __syncthreads();

  float decv = sDec[lane];
  #pragma unroll
  for (int k = 0; k < 2; k++) {
    int c8 = w * 16 + 8 * k;
    #pragma unroll
    for (int j = 0; j < 8; j++)
      *(__bf16*)swaddr(smBd, c8 + j, lane) = (__bf16)((float)bch[k][j] * decv);
  }

  int lr = lane & 15, kb = (lane >> 4) * 8;
  int rl = 16 * w + (lane >> 4) * 4;

  {
    bf16x8 af[2];
    #pragma unroll
    for (int ks = 0; ks < 2; ks++)
      af[ks] = *(const bf16x8*)swaddr(smC, 16 * w + lr, ks * 32 + kb);
    f32x4 g[4] = {};
    #pragma unroll
    for (int nt = 0; nt < 4; nt++)
      #pragma unroll
      for (int ks = 0; ks < 2; ks++) {
        bf16x8 bm = *(const bf16x8*)swaddr(smB, 16 * nt + lr, ks * 32 + kb);
        g[nt] = __builtin_amdgcn_mfma_f32_16x16x32_bf16(af[ks], bm, g[nt], 0, 0, 0);
      }
    #pragma unroll
    for (int nt = 0; nt < 4; nt++)
      #pragma unroll
      for (int q = 0; q < 4; q++) {
        int gl = rl + q, gs = 16 * nt + lr;
        float val = (gl >= gs) ? g[nt][q] * __expf(sAcs[gl] - sAcs[gs]) : 0.f;
        *(__bf16*)swaddr(smG, gl, gs) = (__bf16)val;
      }
  }
  __syncthreads();

  {
    bf16x8 af[2];
    #pragma unroll
    for (int ks = 0; ks < 2; ks++)
      af[ks] = *(const bf16x8*)swaddr(smG, 16 * w + lr, ks * 32 + kb);
    f32x4 y[8] = {};
    #pragma unroll
    for (int nt = 0; nt < 8; nt++)
      #pragma unroll
      for (int ks = 0; ks < 2; ks++) {
        bf16x8 bm = *(const bf16x8*)swaddr(smX, 16 * nt + lr, ks * 32 + kb);
        y[nt] = __builtin_amdgcn_mfma_f32_16x16x32_bf16(af[ks], bm, y[nt], 0, 0, 0);
      }
    #pragma unroll
    for (int nt = 0; nt < 8; nt++)
      #pragma unroll
      for (int q = 0; q < 4; q++)
        Y[(size_t)(row0 + rl + q) * DINNER + h * HEADDIM + 16 * nt + lr] = (__bf16)y[nt][q];
  }

  {
    bf16x8 bfs[4][2];
    #pragma unroll
    for (int nt = 0; nt < 4; nt++)
      #pragma unroll
      for (int ks = 0; ks < 2; ks++)
        bfs[nt][ks] = *(const bf16x8*)swaddr(smBd, 16 * nt + lr, ks * 32 + kb);
    f32x4 s4[2][4] = {};
    #pragma unroll
    for (int mi = 0; mi < 2; mi++) {
      bf16x8 af[2];
      #pragma unroll
      for (int ks = 0; ks < 2; ks++)
        af[ks] = *(const bf16x8*)swaddr(smX, 32 * w + 16 * mi + lr, ks * 32 + kb);
      #pragma unroll
      for (int nt = 0; nt < 4; nt++)
        #pragma unroll
        for (int ks = 0; ks < 2; ks++)
          s4[mi][nt] = __builtin_amdgcn_mfma_f32_16x16x32_bf16(af[ks], bfs[nt][ks], s4[mi][nt], 0, 0, 0);
    }
    __bf16* Sp = S + (((size_t)b * NCHUNK + c) * NHEADS + h) * (HEADDIM * DSTATE);
    #pragma unroll
    for (int mi = 0; mi < 2; mi++)
      #pragma unroll
      for (int nt = 0; nt < 4; nt++)
        #pragma unroll
        for (int q = 0; q < 4; q++) {
          int p = 32 * w + 16 * mi + (lane >> 4) * 4 + q;
          Sp[p * DSTATE + 16 * nt + lr] = (__bf16)s4[mi][nt][q];
        }
  }
}

// ---- K6: inter-chunk scan, in-place S -> prev_states ----
__global__ __launch_bounds__(256) void scan_kernel(
    __bf16* SP, const float* __restrict__ ecs)
{
  int t = blockIdx.x * 256 + threadIdx.x;
  int n = t & 63, p = (t >> 6) & 127, h = (t >> 13) & 15, b = t >> 17;
  float P = 0.f;
  for (int c = 0; c < NCHUNK; c++) {
    size_t idx = (((size_t)b * NCHUNK + c) * NHEADS + h) * (HEADDIM * DSTATE) + (size_t)p * DSTATE + n;
    float s = (float)SP[idx];
    SP[idx] = (__bf16)P;
    float e = ecs[((size_t)b * NHEADS + h) * NCHUNK + c];
    P = e * P + s;
  }
}

// ---- K7 (MFMA): Y += exp(Acs[l]) * (C @ P^T) + D * x  (Y bf16 RMW) ----
__global__ __launch_bounds__(256) void ssd_off_kernel(
    const __bf16* __restrict__ conv, const __bf16* __restrict__ P,
    const float* __restrict__ acs, const float* __restrict__ Dp,
    __bf16* __restrict__ Y)
{
  __shared__ __align__(16) char sm[24832];
  char* smC = sm;
  char* smP = sm + 8192;
  float* eA = (float*)(sm + 24576);
  int bx = blockIdx.x;
  int c = bx & 31, h = (bx >> 5) & 15, b = bx >> 9;
  int t = threadIdx.x;
  int lane = t & 63, w = t >> 6;
  int row0 = b * LL + c * 64;
  #pragma unroll
  for (int k = 0; k < 2; k++) {
    int q = t + 256 * k;
    int lq = q >> 3, c8 = (q & 7) * 8;
    bf16x8 v = *(const bf16x8*)(conv + (size_t)(row0 + lq) * CONVDIM + DINNER + DSTATE + c8);
    *(bf16x8*)swaddr(smC, lq, c8) = v;
  }
  const __bf16* Pp = P + (((size_t)b * NCHUNK + c) * NHEADS + h) * (HEADDIM * DSTATE);
  #pragma unroll
  for (int k = 0; k < 4; k++) {
    int q = t + 256 * k;
    int pr = q >> 3, c8 = (q & 7) * 8;
    bf16x8 v = *(const bf16x8*)(Pp + pr * DSTATE + c8);
    *(bf16x8*)swaddr(smP, pr, c8) = v;
  }
  if (t < 64) eA[t] = __expf(acs[(((size_t)b * NHEADS + h) * NCHUNK + c) * 64 + t]);
  __syncthreads();
  int lr = lane & 15, kb = (lane >> 4) * 8;
  bf16x8 af[2];
  #pragma unroll
  for (int ks = 0; ks < 2; ks++)
    af[ks] = *(const bf16x8*)swaddr(smC, 16 * w + lr, ks * 32 + kb);
  f32x4 y[8] = {};
  #pragma unroll
  for (int nt = 0; nt < 8; nt++)
    #pragma unroll
    for (int ks = 0; ks < 2; ks++) {
      bf16x8 bm = *(const bf16x8*)swaddr(smP, 16 * nt + lr, ks * 32 + kb);
      y[nt] = __builtin_amdgcn_mfma_f32_16x16x32_bf16(af[ks], bm, y[nt], 0, 0, 0);
    }
  float Dh = Dp[h];
  int rl = 16 * w + (lane >> 4) * 4;
  #pragma unroll
  for (int nt = 0; nt < 8; nt++)
    #pragma unroll
    for (int q = 0; q < 4; q++) {
      int l = rl + q;
      int p = 16 * nt + lr;
      size_t yi = (size_t)(row0 + l) * DINNER + h * HEADDIM + p;
      float xsv = (float)conv[(size_t)(row0 + l) * CONVDIM + h * HEADDIM + p];
      Y[yi] = (__bf16)((float)Y[yi] + eA[l] * y[nt][q] + Dh * xsv);
    }
}

// ---- K8: y *= silu(z); RMSNorm; -> bf16 ----
__global__ __launch_bounds__(256) void gate_norm_kernel(
    const __bf16* __restrict__ Y, const __bf16* __restrict__ Z,
    const float* __restrict__ rms_w, __bf16* __restrict__ ybf)
{
  int row = blockIdx.x, t = threadIdx.x;
  float v[8]; float ss = 0.f;
  #pragma unroll
  for (int j = 0; j < 8; j++) {
    int i = t + j * 256;
    float zv = (float)Z[(size_t)row * NPAD + i];
    float yv = (float)Y[(size_t)row * DINNER + i];
    float g = yv * (zv / (1.f + __expf(-zv)));
    v[j] = g; ss += g * g;
  }
  #pragma unroll
  for (int m = 32; m; m >>= 1) ss += __shfl_xor(ss, m);
  __shared__ float red[4];
  if ((t & 63) == 0) red[t >> 6] = ss;
  __syncthreads();
  float tot = red[0] + red[1] + red[2] + red[3];
  float r = rsqrtf(tot * (1.f / DINNER) + 1e-5f);
  #pragma unroll
  for (int j = 0; j < 8; j++) {
    int i = t + j * 256;
    ybf[(size_t)row * DINNER + i] = (__bf16)(v[j] * r * rms_w[i]);
  }
}

extern "C" void kernel_launch(void* const* d_in, const int* in_sizes, int n_in,
                              void* d_out, int out_size, void* d_ws, size_t ws_size,
                              hipStream_t stream) {
  const float* x       = (const float*)d_in[0];
  const float* w_embed = (const float*)d_in[1];
  const float* ln_g    = (const float*)d_in[2];
  const float* ln_b    = (const float*)d_in[3];
  const float* W_in    = (const float*)d_in[4];
  const float* conv_w  = (const float*)d_in[5];
  const float* conv_b  = (const float*)d_in[6];
  const float* dt_bias = (const float*)d_in[7];
  const float* A_log   = (const float*)d_in[8];
  const float* Dp      = (const float*)d_in[9];
  const float* rms_w   = (const float*)d_in[10];
  const float* W_out   = (const float*)d_in[11];
  char* ws = (char*)d_ws;
  __bf16* Ybf  = (__bf16*)(ws + OF_Y);
  __bf16* hbf  = (__bf16*)(ws + OF_HBF);
  __bf16* Wib  = (__bf16*)(ws + OF_WI);
  __bf16* Wob  = (__bf16*)(ws + OF_WO);
  __bf16* Zbf  = (__bf16*)(ws + OF_Z);
  float*  dtb  = (float*)(ws + OF_DT);
  __bf16* convb = (__bf16*)(ws + OF_CONV);
  __bf16* SP   = (__bf16*)(ws + OF_SP);
  float*  acs  = (float*)(ws + OF_ACS);
  float*  ecs  = (float*)(ws + OF_ECS);
  __bf16* ybf  = (__bf16*)(ws + OF_YBF);
  float*  out  = (float*)d_out;

  hipFuncSetAttribute((const void*)gemm256_bt_kernel,
                      hipFuncAttributeMaxDynamicSharedMemorySize, 131072);

  convert_w_kernel<<<2048, 256, 0, stream>>>(W_in, W_out, Wib, Wob);
  embed_ln_kernel<<<ROWS, 256, 0, stream>>>(x, w_embed, ln_g, ln_b, W_in, dt_bias, hbf, dtb);
  gemm256_bt_kernel<<<(ROWS / 256) * (NPAD / 256), 512, 131072, stream>>>(
      hbf, Wib, Zbf, DMODEL, NPAD, NPAD / 256);
  conv_kernel<<<(ROWS * (CONVDIM / 8) + 255) / 256, 256, 0, stream>>>(Zbf, conv_w, conv_b, convb);
  ssd_chunk_kernel<<<BB * NHEADS * NCHUNK, 256, 0, stream>>>(convb, dtb, A_log, Ybf, SP, acs, ecs);
  scan_kernel<<<(BB * NHEADS * HEADDIM * DSTATE) / 256, 256, 0, stream>>>(SP, ecs);
  ssd_off_kernel<<<BB * NHEADS * NCHUNK, 256, 0, stream>>>(convb, SP, acs, Dp, Ybf);
  gate_norm_kernel<<<ROWS, 256, 0, stream>>>(Ybf, Zbf, rms_w, ybf);
  gemm_bt_kernel<float><<<dim3(DMODEL / 128, ROWS / 128), 256, 0, stream>>>(ybf, Wob, out, DINNER, DMODEL);
}

// Round 8
// 279.567 us; speedup vs baseline: 2.0273x; 1.4911x over previous
//
#include <hip/hip_runtime.h>

#define DEV __device__ __forceinline__

typedef __bf16 bf16x8 __attribute__((ext_vector_type(8)));
typedef float f32x4 __attribute__((ext_vector_type(4)));

// ---- constants ----
#define BB 4
#define LL 2048
#define DMODEL 1024
#define DINNER 2048
#define NHEADS 16
#define HEADDIM 128
#define DSTATE 64
#define CONVDIM 2176
#define DINPROJ 4240
#define NCHUNK 32
#define ROWS (BB*LL)   // 8192

// ---- workspace offsets (bytes) ----
#define OF_A    ((size_t)0)            // 8192 f32 = 32 KB
#define OF_ST   ((size_t)32768)        // 2 f32
#define OF_P    ((size_t)65536)        // 4240 f32
#define OF_Q    ((size_t)98304)        // 4240 f32
#define OF_WO   ((size_t)131072)       // 1024*2048*2 = 4 MB
#define OF_CONV ((size_t)8388608)      // 8192*2176*2 = 35651584
#define OF_Y    ((size_t)50331648)     // 8192*2048*2 = 33554432 (bf16)
#define OF_YBF  ((size_t)100663296)    // 8192*2048*2
#define OF_SP   ((size_t)150994944)    // 33554432
#define OF_ACS  ((size_t)190840832)    // 524288
#define OF_ECS  ((size_t)191365120)    // 8192

DEV void gload_lds16(const void* g, void* l) {
  __builtin_amdgcn_global_load_lds((const __attribute__((address_space(1))) void*)g,
                                   (__attribute__((address_space(3))) void*)l, 16, 0, 0);
}

// XOR-swizzled byte address within a [R][64] bf16 tile (rows = 128 B).
DEV char* swaddr(char* base, int r, int c) {
  return base + r * 128 + (((c) * 2) ^ (((r) & 7) << 4));
}

// ---- S0: w_embed stats (1 block) ----
__global__ __launch_bounds__(256) void stats_kernel(
    const float* __restrict__ w, float* __restrict__ st)
{
  int t = threadIdx.x;
  float s = 0.f, s2 = 0.f;
  #pragma unroll
  for (int j = 0; j < 4; j++) { float v = w[t + 256 * j]; s += v; s2 += v * v; }
  #pragma unroll
  for (int m = 32; m; m >>= 1) { s += __shfl_xor(s, m); s2 += __shfl_xor(s2, m); }
  __shared__ float rs[4], rs2[4];
  if ((t & 63) == 0) { rs[t >> 6] = s; rs2[t >> 6] = s2; }
  __syncthreads();
  if (t == 0) {
    float S = rs[0] + rs[1] + rs[2] + rs[3];
    float S2 = rs2[0] + rs2[1] + rs2[2] + rs2[3];
    float mu = S * (1.f / DMODEL);
    st[0] = mu;
    st[1] = S2 * (1.f / DMODEL) - mu * mu;
  }
}

// ---- S1: per-row scalar a_r = x * rsqrt(x^2*var_w + eps) ----
__global__ __launch_bounds__(256) void prep_a_kernel(
    const float* __restrict__ x, const float* __restrict__ st, float* __restrict__ a)
{
  int r = blockIdx.x * 256 + threadIdx.x;
  float varw = st[1];
  float xv = x[r];
  a[r] = xv * rsqrtf(xv * xv * varw + 1e-5f);
}

// ---- S2: GEMV p = ((w-wbar)*g) @ W_in^T ; q = beta @ W_in^T ----
__global__ __launch_bounds__(256) void gemv_kernel(
    const float* __restrict__ w, const float* __restrict__ g,
    const float* __restrict__ beta, const float* __restrict__ st,
    const float* __restrict__ W, float* __restrict__ p, float* __restrict__ q)
{
  int t = threadIdx.x;
  int j = blockIdx.x * 16 + (t >> 4);   // 265 blocks * 16 rows = 4240 exact
  int l16 = t & 15;
  float wbar = st[0];
  const float* Wr = W + (size_t)j * DMODEL;
  float ap = 0.f, aq = 0.f;
  #pragma unroll 4
  for (int jj = 0; jj < 64; jj++) {
    int i = jj * 16 + l16;
    float Wv = Wr[i];
    ap += (w[i] - wbar) * g[i] * Wv;
    aq += beta[i] * Wv;
  }
  #pragma unroll
  for (int m = 8; m; m >>= 1) { ap += __shfl_xor(ap, m, 16); aq += __shfl_xor(aq, m, 16); }
  if (l16 == 0) { p[j] = ap; q[j] = aq; }
}

// ---- S3: W_out fp32 -> bf16 ----
__global__ __launch_bounds__(256) void convert_wo_kernel(
    const float* __restrict__ Wo, __bf16* __restrict__ Wob)
{
  const int NO = DMODEL * DINNER;
  for (int i = blockIdx.x * 256 + threadIdx.x; i < NO; i += gridDim.x * 256)
    Wob[i] = (__bf16)Wo[i];
}

// ---- K4: conv1d + silu from rank-1 xBC: xBC[r,ch] = a_r*px[ch]+qx[ch] ----
__global__ __launch_bounds__(256) void conv2_kernel(
    const float* __restrict__ a, const float* __restrict__ p,
    const float* __restrict__ q, const float* __restrict__ conv_w,
    const float* __restrict__ conv_b, __bf16* __restrict__ out)
{
  int gidx = blockIdx.x * 256 + threadIdx.x;
  if (gidx >= ROWS * (CONVDIM / 8)) return;
  int cg = gidx % (CONVDIM / 8);
  int row = gidx / (CONVDIM / 8);
  int l = row & (LL - 1);
  int ch = cg * 8;
  float av[4];
  #pragma unroll
  for (int k = 0; k < 4; k++) {
    int li = l + k - 3;
    av[k] = (li >= 0) ? a[row + k - 3] : 0.f;
  }
  bf16x8 o;
  #pragma unroll
  for (int jj = 0; jj < 8; jj++) {
    int c = ch + jj;
    f32x4 cw = *(const f32x4*)(conv_w + c * 4);
    float px = p[DINNER + c], qx = q[DINNER + c];
    float sacw = 0.f, scw = 0.f;
    #pragma unroll
    for (int k = 0; k < 4; k++) {
      int li = l + k - 3;
      if (li >= 0) { sacw += av[k] * cw[k]; scw += cw[k]; }
    }
    float val = conv_b[c] + qx * scw + px * sacw;
    o[jj] = (__bf16)(val / (1.f + __expf(-val)));
  }
  *(bf16x8*)(out + (size_t)row * CONVDIM + ch) = o;
}

// ---- K5: per-chunk intra (MFMA): dt inline, Acs, G, Y_diag, chunk states ----
__global__ __launch_bounds__(256) void ssd_chunk_kernel(
    const __bf16* __restrict__ conv, const float* __restrict__ a,
    const float* __restrict__ p, const float* __restrict__ q,
    const float* __restrict__ dt_bias, const float* __restrict__ A_log,
    __bf16* __restrict__ Y, __bf16* __restrict__ S,
    float* __restrict__ acs, float* __restrict__ ecs)
{
  __shared__ __align__(16) char sm[49664];
  char* smC  = sm;
  char* smB  = sm + 8192;
  char* smBd = sm + 16384;
  char* smG  = sm + 24576;
  char* smX  = sm + 32768;
  float* sAcs = (float*)(sm + 49152);
  float* sDec = (float*)(sm + 49408);

  int bx = blockIdx.x;
  int c = bx & 31, h = (bx >> 5) & 15, b = bx >> 9;
  int t = threadIdx.x;
  int lane = t & 63, w = t >> 6;
  int row0 = b * LL + c * 64;
  const __bf16* cr = conv + (size_t)(row0 + lane) * CONVDIM;

  // dt inline from rank-1 in_proj (exact fp32 path)
  float av = a[row0 + lane];
  float vx = av * p[DINNER + CONVDIM + h] + q[DINNER + CONVDIM + h] + dt_bias[h];
  float dtv = vx > 15.f ? vx : log1pf(__expf(vx));

  bf16x8 bch[2], cch[2], xch[4];
  #pragma unroll
  for (int k = 0; k < 2; k++) {
    int c8 = w * 16 + 8 * k;
    bch[k] = *(const bf16x8*)(cr + DINNER + c8);
    cch[k] = *(const bf16x8*)(cr + DINNER + DSTATE + c8);
  }
  #pragma unroll
  for (int k = 0; k < 4; k++)
    xch[k] = *(const bf16x8*)(cr + h * HEADDIM + w * 8 + 32 * k);

  if (t < 64) {
    float Ah = -__expf(A_log[h]);
    float cs = dtv * Ah;
    #pragma unroll
    for (int off = 1; off < 64; off <<= 1) {
      float o = __shfl_up(cs, off);
      if (lane >= off) cs += o;
    }
    float cend = __shfl(cs, 63);
    sAcs[lane] = cs;
    sDec[lane] = __expf(cend - cs);
    acs[(((size_t)b * NHEADS + h) * NCHUNK + c) * 64 + lane] = cs;
    if (lane == 63) ecs[((size_t)b * NHEADS + h) * NCHUNK + c] = __expf(cend);
  }

  #pragma unroll
  for (int k = 0; k < 2; k++) {
    int c8 = w * 16 + 8 * k;
    *(bf16x8*)swaddr(smB, lane, c8) = bch[k];
    *(bf16x8*)swaddr(smC, lane, c8) = cch[k];
  }
  #pragma unroll
  for (int k = 0; k < 4; k++) {
    int p0 = w * 8 + 32 * k;
    #pragma unroll
    for (int j = 0; j < 8; j++)
      *(__bf16*)swaddr(smX, p0 + j, lane) = (__bf16)((float)xch[k][j] * dtv);
  }
  __syncthreads();

  float decv = sDec[lane];
  #pragma unroll
  for (int k = 0; k < 2; k++) {
    int c8 = w * 16 + 8 * k;
    #pragma unroll
    for (int j = 0; j < 8; j++)
      *(__bf16*)swaddr(smBd, c8 + j, lane) = (__bf16)((float)bch[k][j] * decv);
  }

  int lr = lane & 15, kb = (lane >> 4) * 8;
  int rl = 16 * w + (lane >> 4) * 4;

  {
    bf16x8 af[2];
    #pragma unroll
    for (int ks = 0; ks < 2; ks++)
      af[ks] = *(const bf16x8*)swaddr(smC, 16 * w + lr, ks * 32 + kb);
    f32x4 g[4] = {};
    #pragma unroll
    for (int nt = 0; nt < 4; nt++)
      #pragma unroll
      for (int ks = 0; ks < 2; ks++) {
        bf16x8 bm = *(const bf16x8*)swaddr(smB, 16 * nt + lr, ks * 32 + kb);
        g[nt] = __builtin_amdgcn_mfma_f32_16x16x32_bf16(af[ks], bm, g[nt], 0, 0, 0);
      }
    #pragma unroll
    for (int nt = 0; nt < 4; nt++)
      #pragma unroll
      for (int qq = 0; qq < 4; qq++) {
        int gl = rl + qq, gs = 16 * nt + lr;
        float val = (gl >= gs) ? g[nt][qq] * __expf(sAcs[gl] - sAcs[gs]) : 0.f;
        *(__bf16*)swaddr(smG, gl, gs) = (__bf16)val;
      }
  }
  __syncthreads();

  {
    bf16x8 af[2];
    #pragma unroll
    for (int ks = 0; ks < 2; ks++)
      af[ks] = *(const bf16x8*)swaddr(smG, 16 * w + lr, ks * 32 + kb);
    f32x4 y[8] = {};
    #pragma unroll
    for (int nt = 0; nt < 8; nt++)
      #pragma unroll
      for (int ks = 0; ks < 2; ks++) {
        bf16x8 bm = *(const bf16x8*)swaddr(smX, 16 * nt + lr, ks * 32 + kb);
        y[nt] = __builtin_amdgcn_mfma_f32_16x16x32_bf16(af[ks], bm, y[nt], 0, 0, 0);
      }
    #pragma unroll
    for (int nt = 0; nt < 8; nt++)
      #pragma unroll
      for (int qq = 0; qq < 4; qq++)
        Y[(size_t)(row0 + rl + qq) * DINNER + h * HEADDIM + 16 * nt + lr] = (__bf16)y[nt][qq];
  }

  {
    bf16x8 bfs[4][2];
    #pragma unroll
    for (int nt = 0; nt < 4; nt++)
      #pragma unroll
      for (int ks = 0; ks < 2; ks++)
        bfs[nt][ks] = *(const bf16x8*)swaddr(smBd, 16 * nt + lr, ks * 32 + kb);
    f32x4 s4[2][4] = {};
    #pragma unroll
    for (int mi = 0; mi < 2; mi++) {
      bf16x8 af[2];
      #pragma unroll
      for (int ks = 0; ks < 2; ks++)
        af[ks] = *(const bf16x8*)swaddr(smX, 32 * w + 16 * mi + lr, ks * 32 + kb);
      #pragma unroll
      for (int nt = 0; nt < 4; nt++)
        #pragma unroll
        for (int ks = 0; ks < 2; ks++)
          s4[mi][nt] = __builtin_amdgcn_mfma_f32_16x16x32_bf16(af[ks], bfs[nt][ks], s4[mi][nt], 0, 0, 0);
    }
    __bf16* Sp = S + (((size_t)b * NCHUNK + c) * NHEADS + h) * (HEADDIM * DSTATE);
    #pragma unroll
    for (int mi = 0; mi < 2; mi++)
      #pragma unroll
      for (int nt = 0; nt < 4; nt++)
        #pragma unroll
        for (int qq = 0; qq < 4; qq++) {
          int pp = 32 * w + 16 * mi + (lane >> 4) * 4 + qq;
          Sp[pp * DSTATE + 16 * nt + lr] = (__bf16)s4[mi][nt][qq];
        }
  }
}

// ---- K6: inter-chunk scan, in-place S -> prev_states ----
__global__ __launch_bounds__(256) void scan_kernel(
    __bf16* SP, const float* __restrict__ ecs)
{
  int t = blockIdx.x * 256 + threadIdx.x;
  int n = t & 63, p = (t >> 6) & 127, h = (t >> 13) & 15, b = t >> 17;
  float P = 0.f;
  for (int c = 0; c < NCHUNK; c++) {
    size_t idx = (((size_t)b * NCHUNK + c) * NHEADS + h) * (HEADDIM * DSTATE) + (size_t)p * DSTATE + n;
    float s = (float)SP[idx];
    SP[idx] = (__bf16)P;
    float e = ecs[((size_t)b * NHEADS + h) * NCHUNK + c];
    P = e * P + s;
  }
}

// ---- K7 (MFMA): Y += exp(Acs[l]) * (C @ P^T) + D * x  (Y bf16 RMW) ----
__global__ __launch_bounds__(256) void ssd_off_kernel(
    const __bf16* __restrict__ conv, const __bf16* __restrict__ P,
    const float* __restrict__ acs, const float* __restrict__ Dp,
    __bf16* __restrict__ Y)
{
  __shared__ __align__(16) char sm[24832];
  char* smC = sm;
  char* smP = sm + 8192;
  float* eA = (float*)(sm + 24576);
  int bx = blockIdx.x;
  int c = bx & 31, h = (bx >> 5) & 15, b = bx >> 9;
  int t = threadIdx.x;
  int lane = t & 63, w = t >> 6;
  int row0 = b * LL + c * 64;
  #pragma unroll
  for (int k = 0; k < 2; k++) {
    int qg = t + 256 * k;
    int lq = qg >> 3, c8 = (qg & 7) * 8;
    bf16x8 v = *(const bf16x8*)(conv + (size_t)(row0 + lq) * CONVDIM + DINNER + DSTATE + c8);
    *(bf16x8*)swaddr(smC, lq, c8) = v;
  }
  const __bf16* Pp = P + (((size_t)b * NCHUNK + c) * NHEADS + h) * (HEADDIM * DSTATE);
  #pragma unroll
  for (int k = 0; k < 4; k++) {
    int qg = t + 256 * k;
    int pr = qg >> 3, c8 = (qg & 7) * 8;
    bf16x8 v = *(const bf16x8*)(Pp + pr * DSTATE + c8);
    *(bf16x8*)swaddr(smP, pr, c8) = v;
  }
  if (t < 64) eA[t] = __expf(acs[(((size_t)b * NHEADS + h) * NCHUNK + c) * 64 + t]);
  __syncthreads();
  int lr = lane & 15, kb = (lane >> 4) * 8;
  bf16x8 af[2];
  #pragma unroll
  for (int ks = 0; ks < 2; ks++)
    af[ks] = *(const bf16x8*)swaddr(smC, 16 * w + lr, ks * 32 + kb);
  f32x4 y[8] = {};
  #pragma unroll
  for (int nt = 0; nt < 8; nt++)
    #pragma unroll
    for (int ks = 0; ks < 2; ks++) {
      bf16x8 bm = *(const bf16x8*)swaddr(smP, 16 * nt + lr, ks * 32 + kb);
      y[nt] = __builtin_amdgcn_mfma_f32_16x16x32_bf16(af[ks], bm, y[nt], 0, 0, 0);
    }
  float Dh = Dp[h];
  int rl = 16 * w + (lane >> 4) * 4;
  #pragma unroll
  for (int nt = 0; nt < 8; nt++)
    #pragma unroll
    for (int qq = 0; qq < 4; qq++) {
      int l = rl + qq;
      int pp = 16 * nt + lr;
      size_t yi = (size_t)(row0 + l) * DINNER + h * HEADDIM + pp;
      float xsv = (float)conv[(size_t)(row0 + l) * CONVDIM + h * HEADDIM + pp];
      Y[yi] = (__bf16)((float)Y[yi] + eA[l] * y[nt][qq] + Dh * xsv);
    }
}

// ---- K8: y *= silu(z), z from rank-1; RMSNorm; -> bf16 ----
__global__ __launch_bounds__(256) void gate_norm_kernel(
    const __bf16* __restrict__ Y, const float* __restrict__ a,
    const float* __restrict__ p, const float* __restrict__ q,
    const float* __restrict__ rms_w, __bf16* __restrict__ ybf)
{
  int row = blockIdx.x, t = threadIdx.x;
  float ar = a[row];
  float v[8]; float ss = 0.f;
  #pragma unroll
  for (int j = 0; j < 8; j++) {
    int i = t + j * 256;
    float zv = ar * p[i] + q[i];
    float yv = (float)Y[(size_t)row * DINNER + i];
    float g = yv * (zv / (1.f + __expf(-zv)));
    v[j] = g; ss += g * g;
  }
  #pragma unroll
  for (int m = 32; m; m >>= 1) ss += __shfl_xor(ss, m);
  __shared__ float red[4];
  if ((t & 63) == 0) red[t >> 6] = ss;
  __syncthreads();
  float tot = red[0] + red[1] + red[2] + red[3];
  float r = rsqrtf(tot * (1.f / DINNER) + 1e-5f);
  #pragma unroll
  for (int j = 0; j < 8; j++) {
    int i = t + j * 256;
    ybf[(size_t)row * DINNER + i] = (__bf16)(v[j] * r * rms_w[i]);
  }
}

// ---- K9: out_proj 256x128-tile GEMM, grid = 32x8 = 256 blocks (1/CU exact) ----
// C[M,1024] = A[M,2048] @ Bt[1024,2048]^T, f32 out. BK=32, 4-slot ring (96 KiB),
// R4 schedule: stage(kt+3) -> ds_read frags -> MFMA -> counted vmcnt(6) -> barrier.
__global__ __launch_bounds__(512, 2) void gemm_op_kernel(
    const __bf16* __restrict__ A, const __bf16* __restrict__ Bt,
    float* __restrict__ C, int K, int N)
{
  extern __shared__ char sm[];          // A: 4 x 16KB @0, B: 4 x 8KB @65536
  const int t = threadIdx.x;
  const int lane = t & 63, w = t >> 6;
  const int wr = w >> 1, wc = w & 1;    // 4x2 waves, each 64x64 output

  int nbn = gridDim.x;                  // 8
  int nwg = nbn * gridDim.y;            // 256
  int lid = blockIdx.y * nbn + blockIdx.x;
  int wg = (lid & 7) * (nwg >> 3) + (lid >> 3);   // XCD swizzle
  int m0 = (wg / nbn) * 256, n0 = (wg % nbn) * 128;

  int r0, c0, r1, c1;
  {
    int y0 = t * 16, pg0 = y0 >> 7;
    int in0 = (y0 & 127) ^ ((pg0 & 7) << 4);
    r0 = pg0 * 2 + (in0 >> 6); c0 = in0 & 63;
    int y1 = 8192 + t * 16, pg1 = y1 >> 7;
    int in1 = (y1 & 127) ^ ((pg1 & 7) << 4);
    r1 = pg1 * 2 + (in1 >> 6); c1 = in1 & 63;
  }
  const char* pA0 = (const char*)A + (size_t)(m0 + r0) * (2 * K) + c0;
  const char* pA1 = (const char*)A + (size_t)(m0 + r1) * (2 * K) + c1;
  const char* pB0 = (const char*)Bt + (size_t)(n0 + r0) * (2 * K) + c0;

  const int lr = lane & 15, kg = lane >> 4;
  int rA = wr * 64 + lr, pgA = rA >> 1;
  const int offA = pgA * 128 + ((((rA & 1) << 6) | (kg << 4)) ^ ((pgA & 7) << 4));
  int rB = wc * 64 + lr, pgB = rB >> 1;
  const int offB = pgB * 128 + ((((rB & 1) << 6) | (kg << 4)) ^ ((pgB & 7) << 4));

  f32x4 acc[4][4] = {};
  const int KT = K >> 5;

  #define STG(slot) do { \
    char* la_ = sm + (slot) * 16384; \
    char* lb_ = sm + 65536 + (slot) * 8192; \
    gload_lds16(pA0, la_ + t * 16); \
    gload_lds16(pA1, la_ + 8192 + t * 16); \
    gload_lds16(pB0, lb_ + t * 16); \
    pA0 += 64; pA1 += 64; pB0 += 64; \
  } while (0)

  STG(0); STG(1); STG(2);
  asm volatile("s_waitcnt vmcnt(6)" ::: "memory");
  __builtin_amdgcn_sched_barrier(0);
  __builtin_amdgcn_s_barrier();

  for (int kt = 0; kt < KT; ++kt) {
    int s = kt & 3;
    if (kt + 3 < KT) STG((kt + 3) & 3);
    const char* sa = sm + s * 16384;
    const char* sb = sm + 65536 + s * 8192;
    bf16x8 af[4], bfr[4];
    #pragma unroll
    for (int m = 0; m < 4; m++) af[m] = *(const bf16x8*)(sa + offA + m * 1024);
    #pragma unroll
    for (int n = 0; n < 4; n++) bfr[n] = *(const bf16x8*)(sb + offB + n * 1024);
    __builtin_amdgcn_s_setprio(1);
    #pragma unroll
    for (int m = 0; m < 4; m++)
      #pragma unroll
      for (int n = 0; n < 4; n++)
        acc[m][n] = __builtin_amdgcn_mfma_f32_16x16x32_bf16(af[m], bfr[n], acc[m][n], 0, 0, 0);
    __builtin_amdgcn_s_setprio(0);
    if (kt + 3 < KT)      { asm volatile("s_waitcnt vmcnt(6)" ::: "memory"); }
    else if (kt + 2 < KT) { asm volatile("s_waitcnt vmcnt(3)" ::: "memory"); }
    else if (kt + 1 < KT) { asm volatile("s_waitcnt vmcnt(0)" ::: "memory"); }
    __builtin_amdgcn_sched_barrier(0);
    __builtin_amdgcn_s_barrier();
  }
  #undef STG

  #pragma unroll
  for (int m = 0; m < 4; m++)
    #pragma unroll
    for (int n = 0; n < 4; n++)
      #pragma unroll
      for (int qq = 0; qq < 4; qq++) {
        int row = m0 + wr * 64 + m * 16 + kg * 4 + qq;
        int col = n0 + wc * 64 + n * 16 + lr;
        C[(size_t)row * N + col] = acc[m][n][qq];
      }
}

extern "C" void kernel_launch(void* const* d_in, const int* in_sizes, int n_in,
                              void* d_out, int out_size, void* d_ws, size_t ws_size,
                              hipStream_t stream) {
  const float* x       = (const float*)d_in[0];
  const float* w_embed = (const float*)d_in[1];
  const float* ln_g    = (const float*)d_in[2];
  const float* ln_b    = (const float*)d_in[3];
  const float* W_in    = (const float*)d_in[4];
  const float* conv_w  = (const float*)d_in[5];
  const float* conv_b  = (const float*)d_in[6];
  const float* dt_bias = (const float*)d_in[7];
  const float* A_log   = (const float*)d_in[8];
  const float* Dp      = (const float*)d_in[9];
  const float* rms_w   = (const float*)d_in[10];
  const float* W_out   = (const float*)d_in[11];
  char* ws = (char*)d_ws;
  float*  aR   = (float*)(ws + OF_A);
  float*  st   = (float*)(ws + OF_ST);
  float*  pV   = (float*)(ws + OF_P);
  float*  qV   = (float*)(ws + OF_Q);
  __bf16* Wob  = (__bf16*)(ws + OF_WO);
  __bf16* convb = (__bf16*)(ws + OF_CONV);
  __bf16* Ybf  = (__bf16*)(ws + OF_Y);
  __bf16* ybf  = (__bf16*)(ws + OF_YBF);
  __bf16* SP   = (__bf16*)(ws + OF_SP);
  float*  acs  = (float*)(ws + OF_ACS);
  float*  ecs  = (float*)(ws + OF_ECS);
  float*  out  = (float*)d_out;

  hipFuncSetAttribute((const void*)gemm_op_kernel,
                      hipFuncAttributeMaxDynamicSharedMemorySize, 98304);

  stats_kernel<<<1, 256, 0, stream>>>(w_embed, st);
  prep_a_kernel<<<ROWS / 256, 256, 0, stream>>>(x, st, aR);
  gemv_kernel<<<DINPROJ / 16, 256, 0, stream>>>(w_embed, ln_g, ln_b, st, W_in, pV, qV);
  convert_wo_kernel<<<1024, 256, 0, stream>>>(W_out, Wob);
  conv2_kernel<<<(ROWS * (CONVDIM / 8) + 255) / 256, 256, 0, stream>>>(
      aR, pV, qV, conv_w, conv_b, convb);
  ssd_chunk_kernel<<<BB * NHEADS * NCHUNK, 256, 0, stream>>>(
      convb, aR, pV, qV, dt_bias, A_log, Ybf, SP, acs, ecs);
  scan_kernel<<<(BB * NHEADS * HEADDIM * DSTATE) / 256, 256, 0, stream>>>(SP, ecs);
  ssd_off_kernel<<<BB * NHEADS * NCHUNK, 256, 0, stream>>>(convb, SP, acs, Dp, Ybf);
  gate_norm_kernel<<<ROWS, 256, 0, stream>>>(Ybf, aR, pV, qV, rms_w, ybf);
  gemm_op_kernel<<<dim3(8, 32), 512, 98304, stream>>>(ybf, Wob, out, DINNER, DMODEL);
}

// Round 9
// 255.339 us; speedup vs baseline: 2.2197x; 1.0949x over previous
//
#include <hip/hip_runtime.h>

#define DEV __device__ __forceinline__

typedef __bf16 bf16x8 __attribute__((ext_vector_type(8)));
typedef float f32x4 __attribute__((ext_vector_type(4)));

// ---- constants ----
#define BB 4
#define LL 2048
#define DMODEL 1024
#define DINNER 2048
#define NHEADS 16
#define HEADDIM 128
#define DSTATE 64
#define CONVDIM 2176
#define DINPROJ 4240
#define NCHUNK 32
#define ROWS (BB*LL)   // 8192

// ---- workspace offsets (bytes) ----
#define OF_A    ((size_t)0)            // 8192 f32
#define OF_ST   ((size_t)32768)        // 2 f32
#define OF_P    ((size_t)65536)        // 4240 f32
#define OF_Q    ((size_t)98304)        // 4240 f32
#define OF_WO   ((size_t)131072)       // 4 MB
#define OF_Y    ((size_t)50331648)     // 33.5 MB bf16
#define OF_YBF  ((size_t)100663296)    // 33.5 MB bf16
#define OF_SP   ((size_t)150994944)    // 33.5 MB bf16
#define OF_ACS  ((size_t)190840832)    // 512 KB
#define OF_ECS  ((size_t)191365120)    // 8 KB

DEV void gload_lds16(const void* g, void* l) {
  __builtin_amdgcn_global_load_lds((const __attribute__((address_space(1))) void*)g,
                                   (__attribute__((address_space(3))) void*)l, 16, 0, 0);
}

// XOR-swizzled byte address within a [R][64] bf16 tile (rows = 128 B).
DEV char* swaddr(char* base, int r, int c) {
  return base + r * 128 + (((c) * 2) ^ (((r) & 7) << 4));
}

// conv1d+silu for channel ch (conv-space), given a-window av[4] and mask mk[4]
DEV float convsilu(int ch, const float* __restrict__ conv_w, const float* __restrict__ conv_b,
                   const float* __restrict__ p, const float* __restrict__ q,
                   const float av[4], const float mk[4]) {
  f32x4 w4 = *(const f32x4*)(conv_w + ch * 4);
  float sa = av[0] * w4[0] + av[1] * w4[1] + av[2] * w4[2] + av[3] * w4[3];
  float sm = mk[0] * w4[0] + mk[1] * w4[1] + mk[2] * w4[2] + mk[3] * w4[3];
  float val = conv_b[ch] + q[DINNER + ch] * sm + p[DINNER + ch] * sa;
  return val / (1.f + __expf(-val));
}

// ---- S0: w_embed stats (1 block) ----
__global__ __launch_bounds__(256) void stats_kernel(
    const float* __restrict__ w, float* __restrict__ st)
{
  int t = threadIdx.x;
  float s = 0.f, s2 = 0.f;
  #pragma unroll
  for (int j = 0; j < 4; j++) { float v = w[t + 256 * j]; s += v; s2 += v * v; }
  #pragma unroll
  for (int m = 32; m; m >>= 1) { s += __shfl_xor(s, m); s2 += __shfl_xor(s2, m); }
  __shared__ float rs[4], rs2[4];
  if ((t & 63) == 0) { rs[t >> 6] = s; rs2[t >> 6] = s2; }
  __syncthreads();
  if (t == 0) {
    float S = rs[0] + rs[1] + rs[2] + rs[3];
    float S2 = rs2[0] + rs2[1] + rs2[2] + rs2[3];
    float mu = S * (1.f / DMODEL);
    st[0] = mu;
    st[1] = S2 * (1.f / DMODEL) - mu * mu;
  }
}

// ---- S1: per-row scalar a_r = x * rsqrt(x^2*var_w + eps) ----
__global__ __launch_bounds__(256) void prep_a_kernel(
    const float* __restrict__ x, const float* __restrict__ st, float* __restrict__ a)
{
  int r = blockIdx.x * 256 + threadIdx.x;
  float varw = st[1];
  float xv = x[r];
  a[r] = xv * rsqrtf(xv * xv * varw + 1e-5f);
}

// ---- S2: GEMV p = ((w-wbar)*g) @ W_in^T ; q = beta @ W_in^T ----
__global__ __launch_bounds__(256) void gemv_kernel(
    const float* __restrict__ w, const float* __restrict__ g,
    const float* __restrict__ beta, const float* __restrict__ st,
    const float* __restrict__ W, float* __restrict__ p, float* __restrict__ q)
{
  int t = threadIdx.x;
  int j = blockIdx.x * 16 + (t >> 4);
  int l16 = t & 15;
  float wbar = st[0];
  const float* Wr = W + (size_t)j * DMODEL;
  float ap = 0.f, aq = 0.f;
  #pragma unroll 4
  for (int jj = 0; jj < 64; jj++) {
    int i = jj * 16 + l16;
    float Wv = Wr[i];
    ap += (w[i] - wbar) * g[i] * Wv;
    aq += beta[i] * Wv;
  }
  #pragma unroll
  for (int m = 8; m; m >>= 1) { ap += __shfl_xor(ap, m, 16); aq += __shfl_xor(aq, m, 16); }
  if (l16 == 0) { p[j] = ap; q[j] = aq; }
}

// ---- S3: W_out fp32 -> bf16 ----
__global__ __launch_bounds__(256) void convert_wo_kernel(
    const float* __restrict__ Wo, __bf16* __restrict__ Wob)
{
  const int NO = DMODEL * DINNER;
  for (int i = blockIdx.x * 256 + threadIdx.x; i < NO; i += gridDim.x * 256)
    Wob[i] = (__bf16)Wo[i];
}

// ---- K5: per-chunk intra (MFMA), conv computed INLINE from rank-1 ----
__global__ __launch_bounds__(256) void ssd_chunk_kernel(
    const float* __restrict__ a, const float* __restrict__ p,
    const float* __restrict__ q, const float* __restrict__ conv_w,
    const float* __restrict__ conv_b, const float* __restrict__ dt_bias,
    const float* __restrict__ A_log,
    __bf16* __restrict__ Y, __bf16* __restrict__ S,
    float* __restrict__ acs, float* __restrict__ ecs)
{
  __shared__ __align__(16) char sm[49664];
  char* smC  = sm;
  char* smB  = sm + 8192;
  char* smBd = sm + 16384;
  char* smG  = sm + 24576;
  char* smX  = sm + 32768;
  float* sAcs = (float*)(sm + 49152);
  float* sDec = (float*)(sm + 49408);

  int bx = blockIdx.x;
  int c = bx & 31, h = (bx >> 5) & 15, b = bx >> 9;
  int t = threadIdx.x;
  int lane = t & 63, w = t >> 6;
  int row0 = b * LL + c * 64;

  // a-window + mask for this thread's row (lane)
  float av[4], mk[4];
  {
    int lg = c * 64 + lane;
    #pragma unroll
    for (int k = 0; k < 4; k++) {
      int li = lg + k - 3;
      bool v = li >= 0;
      av[k] = v ? a[b * LL + li] : 0.f;
      mk[k] = v ? 1.f : 0.f;
    }
  }

  // dt inline (exact fp32); av[3] = a at this row
  float vx = av[3] * p[DINNER + CONVDIM + h] + q[DINNER + CONVDIM + h] + dt_bias[h];
  float dtv = vx > 15.f ? vx : log1pf(__expf(vx));

  // inline conv: B, C (kept in f32 regs for BdT), X (scaled by dt -> LDS)
  float bv[16];
  #pragma unroll
  for (int k = 0; k < 2; k++) {
    int c8 = w * 16 + 8 * k;
    bf16x8 vb, vc;
    #pragma unroll
    for (int j = 0; j < 8; j++) {
      int n = c8 + j;
      float bb = convsilu(2048 + n, conv_w, conv_b, p, q, av, mk);
      float cc = convsilu(2112 + n, conv_w, conv_b, p, q, av, mk);
      bv[8 * k + j] = bb;
      vb[j] = (__bf16)bb;
      vc[j] = (__bf16)cc;
    }
    *(bf16x8*)swaddr(smB, lane, c8) = vb;
    *(bf16x8*)swaddr(smC, lane, c8) = vc;
  }
  #pragma unroll
  for (int k = 0; k < 4; k++) {
    int p0 = w * 8 + 32 * k;
    #pragma unroll
    for (int j = 0; j < 8; j++) {
      float xv2 = convsilu(h * HEADDIM + p0 + j, conv_w, conv_b, p, q, av, mk);
      *(__bf16*)swaddr(smX, p0 + j, lane) = (__bf16)(xv2 * dtv);
    }
  }

  // wave 0: inclusive scan of dA -> Acs, dec
  if (t < 64) {
    float Ah = -__expf(A_log[h]);
    float cs = dtv * Ah;
    #pragma unroll
    for (int off = 1; off < 64; off <<= 1) {
      float o = __shfl_up(cs, off);
      if (lane >= off) cs += o;
    }
    float cend = __shfl(cs, 63);
    sAcs[lane] = cs;
    sDec[lane] = __expf(cend - cs);
    acs[(((size_t)b * NHEADS + h) * NCHUNK + c) * 64 + lane] = cs;
    if (lane == 63) ecs[((size_t)b * NHEADS + h) * NCHUNK + c] = __expf(cend);
  }
  __syncthreads();

  float decv = sDec[lane];
  #pragma unroll
  for (int k = 0; k < 2; k++) {
    int c8 = w * 16 + 8 * k;
    #pragma unroll
    for (int j = 0; j < 8; j++)
      *(__bf16*)swaddr(smBd, c8 + j, lane) = (__bf16)(bv[8 * k + j] * decv);
  }

  int lr = lane & 15, kb = (lane >> 4) * 8;
  int rl = 16 * w + (lane >> 4) * 4;

  {
    bf16x8 af[2];
    #pragma unroll
    for (int ks = 0; ks < 2; ks++)
      af[ks] = *(const bf16x8*)swaddr(smC, 16 * w + lr, ks * 32 + kb);
    f32x4 g[4] = {};
    #pragma unroll
    for (int nt = 0; nt < 4; nt++)
      #pragma unroll
      for (int ks = 0; ks < 2; ks++) {
        bf16x8 bm = *(const bf16x8*)swaddr(smB, 16 * nt + lr, ks * 32 + kb);
        g[nt] = __builtin_amdgcn_mfma_f32_16x16x32_bf16(af[ks], bm, g[nt], 0, 0, 0);
      }
    #pragma unroll
    for (int nt = 0; nt < 4; nt++)
      #pragma unroll
      for (int qq = 0; qq < 4; qq++) {
        int gl = rl + qq, gs = 16 * nt + lr;
        float val = (gl >= gs) ? g[nt][qq] * __expf(sAcs[gl] - sAcs[gs]) : 0.f;
        *(__bf16*)swaddr(smG, gl, gs) = (__bf16)val;
      }
  }
  __syncthreads();

  {
    bf16x8 af[2];
    #pragma unroll
    for (int ks = 0; ks < 2; ks++)
      af[ks] = *(const bf16x8*)swaddr(smG, 16 * w + lr, ks * 32 + kb);
    f32x4 y[8] = {};
    #pragma unroll
    for (int nt = 0; nt < 8; nt++)
      #pragma unroll
      for (int ks = 0; ks < 2; ks++) {
        bf16x8 bm = *(const bf16x8*)swaddr(smX, 16 * nt + lr, ks * 32 + kb);
        y[nt] = __builtin_amdgcn_mfma_f32_16x16x32_bf16(af[ks], bm, y[nt], 0, 0, 0);
      }
    #pragma unroll
    for (int nt = 0; nt < 8; nt++)
      #pragma unroll
      for (int qq = 0; qq < 4; qq++)
        Y[(size_t)(row0 + rl + qq) * DINNER + h * HEADDIM + 16 * nt + lr] = (__bf16)y[nt][qq];
  }

  {
    bf16x8 bfs[4][2];
    #pragma unroll
    for (int nt = 0; nt < 4; nt++)
      #pragma unroll
      for (int ks = 0; ks < 2; ks++)
        bfs[nt][ks] = *(const bf16x8*)swaddr(smBd, 16 * nt + lr, ks * 32 + kb);
    f32x4 s4[2][4] = {};
    #pragma unroll
    for (int mi = 0; mi < 2; mi++) {
      bf16x8 af[2];
      #pragma unroll
      for (int ks = 0; ks < 2; ks++)
        af[ks] = *(const bf16x8*)swaddr(smX, 32 * w + 16 * mi + lr, ks * 32 + kb);
      #pragma unroll
      for (int nt = 0; nt < 4; nt++)
        #pragma unroll
        for (int ks = 0; ks < 2; ks++)
          s4[mi][nt] = __builtin_amdgcn_mfma_f32_16x16x32_bf16(af[ks], bfs[nt][ks], s4[mi][nt], 0, 0, 0);
    }
    __bf16* Sp = S + (((size_t)b * NCHUNK + c) * NHEADS + h) * (HEADDIM * DSTATE);
    #pragma unroll
    for (int mi = 0; mi < 2; mi++)
      #pragma unroll
      for (int nt = 0; nt < 4; nt++)
        #pragma unroll
        for (int qq = 0; qq < 4; qq++) {
          int pp = 32 * w + 16 * mi + (lane >> 4) * 4 + qq;
          Sp[pp * DSTATE + 16 * nt + lr] = (__bf16)s4[mi][nt][qq];
        }
  }
}

// ---- K6: inter-chunk scan, in-place S -> prev_states ----
__global__ __launch_bounds__(256) void scan_kernel(
    __bf16* SP, const float* __restrict__ ecs)
{
  int t = blockIdx.x * 256 + threadIdx.x;
  int n = t & 63, p = (t >> 6) & 127, h = (t >> 13) & 15, b = t >> 17;
  float P = 0.f;
  for (int c = 0; c < NCHUNK; c++) {
    size_t idx = (((size_t)b * NCHUNK + c) * NHEADS + h) * (HEADDIM * DSTATE) + (size_t)p * DSTATE + n;
    float s = (float)SP[idx];
    SP[idx] = (__bf16)P;
    float e = ecs[((size_t)b * NHEADS + h) * NCHUNK + c];
    P = e * P + s;
  }
}

// ---- K7 (MFMA): Y += exp(Acs[l]) * (C @ P^T) + D * x, conv INLINE ----
__global__ __launch_bounds__(256) void ssd_off_kernel(
    const float* __restrict__ a, const float* __restrict__ p,
    const float* __restrict__ q, const float* __restrict__ conv_w,
    const float* __restrict__ conv_b, const __bf16* __restrict__ P,
    const float* __restrict__ acs, const float* __restrict__ Dp,
    __bf16* __restrict__ Y)
{
  __shared__ __align__(16) char sm[25408];
  char* smC = sm;
  char* smP = sm + 8192;
  float* eA = (float*)(sm + 24576);
  float* sA = (float*)(sm + 24832);   // a-window: sA[i] = a[row0 + i - 3] (0 if invalid)
  int bx = blockIdx.x;
  int c = bx & 31, h = (bx >> 5) & 15, b = bx >> 9;
  int t = threadIdx.x;
  int lane = t & 63, w = t >> 6;
  int row0 = b * LL + c * 64;

  // C tile inline (row = lane, wave covers 16 channels)
  {
    float av[4], mk[4];
    int lg = c * 64 + lane;
    #pragma unroll
    for (int k = 0; k < 4; k++) {
      int li = lg + k - 3;
      bool v = li >= 0;
      av[k] = v ? a[b * LL + li] : 0.f;
      mk[k] = v ? 1.f : 0.f;
    }
    #pragma unroll
    for (int k = 0; k < 2; k++) {
      int c8 = w * 16 + 8 * k;
      bf16x8 vc;
      #pragma unroll
      for (int j = 0; j < 8; j++)
        vc[j] = (__bf16)convsilu(2112 + c8 + j, conv_w, conv_b, p, q, av, mk);
      *(bf16x8*)swaddr(smC, lane, c8) = vc;
    }
  }
  if (t < 67) {
    int li = c * 64 + t - 3;
    sA[t] = (li >= 0) ? a[b * LL + li] : 0.f;
  }
  const __bf16* Pp = P + (((size_t)b * NCHUNK + c) * NHEADS + h) * (HEADDIM * DSTATE);
  #pragma unroll
  for (int k = 0; k < 4; k++) {
    int qg = t + 256 * k;
    int pr = qg >> 3, c8 = (qg & 7) * 8;
    bf16x8 v = *(const bf16x8*)(Pp + pr * DSTATE + c8);
    *(bf16x8*)swaddr(smP, pr, c8) = v;
  }
  if (t < 64) eA[t] = __expf(acs[(((size_t)b * NHEADS + h) * NCHUNK + c) * 64 + t]);
  __syncthreads();

  int lr = lane & 15, kb = (lane >> 4) * 8;
  bf16x8 af[2];
  #pragma unroll
  for (int ks = 0; ks < 2; ks++)
    af[ks] = *(const bf16x8*)swaddr(smC, 16 * w + lr, ks * 32 + kb);
  f32x4 y[8] = {};
  #pragma unroll
  for (int nt = 0; nt < 8; nt++)
    #pragma unroll
    for (int ks = 0; ks < 2; ks++) {
      bf16x8 bm = *(const bf16x8*)swaddr(smP, 16 * nt + lr, ks * 32 + kb);
      y[nt] = __builtin_amdgcn_mfma_f32_16x16x32_bf16(af[ks], bm, y[nt], 0, 0, 0);
    }
  float Dh = Dp[h];
  int rl = 16 * w + (lane >> 4) * 4;
  #pragma unroll
  for (int nt = 0; nt < 8; nt++) {
    int ch = h * HEADDIM + 16 * nt + lr;
    f32x4 w4 = *(const f32x4*)(conv_w + ch * 4);
    float cb = conv_b[ch], px = p[DINNER + ch], qx = q[DINNER + ch];
    #pragma unroll
    for (int qq = 0; qq < 4; qq++) {
      int l = rl + qq;
      float sa = sA[l] * w4[0] + sA[l + 1] * w4[1] + sA[l + 2] * w4[2] + sA[l + 3] * w4[3];
      float smv;
      if (c > 0) smv = w4[0] + w4[1] + w4[2] + w4[3];
      else {
        smv = w4[3];
        #pragma unroll
        for (int k = 0; k < 3; k++) if (l + k >= 3) smv += w4[k];
      }
      float val = cb + qx * smv + px * sa;
      float xsv = val / (1.f + __expf(-val));
      size_t yi = (size_t)(row0 + l) * DINNER + ch;
      Y[yi] = (__bf16)((float)Y[yi] + eA[l] * y[nt][qq] + Dh * xsv);
    }
  }
}

// ---- K8: y *= silu(z), z from rank-1; RMSNorm; -> bf16 ----
__global__ __launch_bounds__(256) void gate_norm_kernel(
    const __bf16* __restrict__ Y, const float* __restrict__ a,
    const float* __restrict__ p, const float* __restrict__ q,
    const float* __restrict__ rms_w, __bf16* __restrict__ ybf)
{
  int row = blockIdx.x, t = threadIdx.x;
  float ar = a[row];
  float v[8]; float ss = 0.f;
  #pragma unroll
  for (int j = 0; j < 8; j++) {
    int i = t + j * 256;
    float zv = ar * p[i] + q[i];
    float yv = (float)Y[(size_t)row * DINNER + i];
    float g = yv * (zv / (1.f + __expf(-zv)));
    v[j] = g; ss += g * g;
  }
  #pragma unroll
  for (int m = 32; m; m >>= 1) ss += __shfl_xor(ss, m);
  __shared__ float red[4];
  if ((t & 63) == 0) red[t >> 6] = ss;
  __syncthreads();
  float tot = red[0] + red[1] + red[2] + red[3];
  float r = rsqrtf(tot * (1.f / DINNER) + 1e-5f);
  #pragma unroll
  for (int j = 0; j < 8; j++) {
    int i = t + j * 256;
    ybf[(size_t)row * DINNER + i] = (__bf16)(v[j] * r * rms_w[i]);
  }
}

// ---- K9: out_proj 256x128-tile GEMM, grid = 32x8 = 256 blocks ----
__global__ __launch_bounds__(512, 2) void gemm_op_kernel(
    const __bf16* __restrict__ A, const __bf16* __restrict__ Bt,
    float* __restrict__ C, int K, int N)
{
  extern __shared__ char sm[];          // A: 4 x 16KB @0, B: 4 x 8KB @65536
  const int t = threadIdx.x;
  const int lane = t & 63, w = t >> 6;
  const int wr = w >> 1, wc = w & 1;

  int nbn = gridDim.x;                  // 8
  int nwg = nbn * gridDim.y;            // 256
  int lid = blockIdx.y * nbn + blockIdx.x;
  int wg = (lid & 7) * (nwg >> 3) + (lid >> 3);
  int m0 = (wg / nbn) * 256, n0 = (wg % nbn) * 128;

  int r0, c0, r1, c1;
  {
    int y0 = t * 16, pg0 = y0 >> 7;
    int in0 = (y0 & 127) ^ ((pg0 & 7) << 4);
    r0 = pg0 * 2 + (in0 >> 6); c0 = in0 & 63;
    int y1 = 8192 + t * 16, pg1 = y1 >> 7;
    int in1 = (y1 & 127) ^ ((pg1 & 7) << 4);
    r1 = pg1 * 2 + (in1 >> 6); c1 = in1 & 63;
  }
  const char* pA0 = (const char*)A + (size_t)(m0 + r0) * (2 * K) + c0;
  const char* pA1 = (const char*)A + (size_t)(m0 + r1) * (2 * K) + c1;
  const char* pB0 = (const char*)Bt + (size_t)(n0 + r0) * (2 * K) + c0;

  const int lr = lane & 15, kg = lane >> 4;
  int rA = wr * 64 + lr, pgA = rA >> 1;
  const int offA = pgA * 128 + ((((rA & 1) << 6) | (kg << 4)) ^ ((pgA & 7) << 4));
  int rB = wc * 64 + lr, pgB = rB >> 1;
  const int offB = pgB * 128 + ((((rB & 1) << 6) | (kg << 4)) ^ ((pgB & 7) << 4));

  f32x4 acc[4][4] = {};
  const int KT = K >> 5;

  #define STG(slot) do { \
    char* la_ = sm + (slot) * 16384; \
    char* lb_ = sm + 65536 + (slot) * 8192; \
    gload_lds16(pA0, la_ + t * 16); \
    gload_lds16(pA1, la_ + 8192 + t * 16); \
    gload_lds16(pB0, lb_ + t * 16); \
    pA0 += 64; pA1 += 64; pB0 += 64; \
  } while (0)

  STG(0); STG(1); STG(2);
  asm volatile("s_waitcnt vmcnt(6)" ::: "memory");
  __builtin_amdgcn_sched_barrier(0);
  __builtin_amdgcn_s_barrier();

  for (int kt = 0; kt < KT; ++kt) {
    int s = kt & 3;
    if (kt + 3 < KT) STG((kt + 3) & 3);
    const char* sa = sm + s * 16384;
    const char* sb = sm + 65536 + s * 8192;
    bf16x8 af[4], bfr[4];
    #pragma unroll
    for (int m = 0; m < 4; m++) af[m] = *(const bf16x8*)(sa + offA + m * 1024);
    #pragma unroll
    for (int n = 0; n < 4; n++) bfr[n] = *(const bf16x8*)(sb + offB + n * 1024);
    __builtin_amdgcn_s_setprio(1);
    #pragma unroll
    for (int m = 0; m < 4; m++)
      #pragma unroll
      for (int n = 0; n < 4; n++)
        acc[m][n] = __builtin_amdgcn_mfma_f32_16x16x32_bf16(af[m], bfr[n], acc[m][n], 0, 0, 0);
    __builtin_amdgcn_s_setprio(0);
    if (kt + 3 < KT)      { asm volatile("s_waitcnt vmcnt(6)" ::: "memory"); }
    else if (kt + 2 < KT) { asm volatile("s_waitcnt vmcnt(3)" ::: "memory"); }
    else if (kt + 1 < KT) { asm volatile("s_waitcnt vmcnt(0)" ::: "memory"); }
    __builtin_amdgcn_sched_barrier(0);
    __builtin_amdgcn_s_barrier();
  }
  #undef STG

  #pragma unroll
  for (int m = 0; m < 4; m++)
    #pragma unroll
    for (int n = 0; n < 4; n++)
      #pragma unroll
      for (int qq = 0; qq < 4; qq++) {
        int row = m0 + wr * 64 + m * 16 + kg * 4 + qq;
        int col = n0 + wc * 64 + n * 16 + lr;
        C[(size_t)row * N + col] = acc[m][n][qq];
      }
}

extern "C" void kernel_launch(void* const* d_in, const int* in_sizes, int n_in,
                              void* d_out, int out_size, void* d_ws, size_t ws_size,
                              hipStream_t stream) {
  const float* x       = (const float*)d_in[0];
  const float* w_embed = (const float*)d_in[1];
  const float* ln_g    = (const float*)d_in[2];
  const float* ln_b    = (const float*)d_in[3];
  const float* W_in    = (const float*)d_in[4];
  const float* conv_w  = (const float*)d_in[5];
  const float* conv_b  = (const float*)d_in[6];
  const float* dt_bias = (const float*)d_in[7];
  const float* A_log   = (const float*)d_in[8];
  const float* Dp      = (const float*)d_in[9];
  const float* rms_w   = (const float*)d_in[10];
  const float* W_out   = (const float*)d_in[11];
  char* ws = (char*)d_ws;
  float*  aR   = (float*)(ws + OF_A);
  float*  st   = (float*)(ws + OF_ST);
  float*  pV   = (float*)(ws + OF_P);
  float*  qV   = (float*)(ws + OF_Q);
  __bf16* Wob  = (__bf16*)(ws + OF_WO);
  __bf16* Ybf  = (__bf16*)(ws + OF_Y);
  __bf16* ybf  = (__bf16*)(ws + OF_YBF);
  __bf16* SP   = (__bf16*)(ws + OF_SP);
  float*  acs  = (float*)(ws + OF_ACS);
  float*  ecs  = (float*)(ws + OF_ECS);
  float*  out  = (float*)d_out;

  hipFuncSetAttribute((const void*)gemm_op_kernel,
                      hipFuncAttributeMaxDynamicSharedMemorySize, 98304);

  stats_kernel<<<1, 256, 0, stream>>>(w_embed, st);
  prep_a_kernel<<<ROWS / 256, 256, 0, stream>>>(x, st, aR);
  gemv_kernel<<<DINPROJ / 16, 256, 0, stream>>>(w_embed, ln_g, ln_b, st, W_in, pV, qV);
  convert_wo_kernel<<<1024, 256, 0, stream>>>(W_out, Wob);
  ssd_chunk_kernel<<<BB * NHEADS * NCHUNK, 256, 0, stream>>>(
      aR, pV, qV, conv_w, conv_b, dt_bias, A_log, Ybf, SP, acs, ecs);
  scan_kernel<<<(BB * NHEADS * HEADDIM * DSTATE) / 256, 256, 0, stream>>>(SP, ecs);
  ssd_off_kernel<<<BB * NHEADS * NCHUNK, 256, 0, stream>>>(
      aR, pV, qV, conv_w, conv_b, SP, acs, Dp, Ybf);
  gate_norm_kernel<<<ROWS, 256, 0, stream>>>(Ybf, aR, pV, qV, rms_w, ybf);
  gemm_op_kernel<<<dim3(8, 32), 512, 98304, stream>>>(ybf, Wob, out, DINNER, DMODEL);
}

// Round 10
// 238.996 us; speedup vs baseline: 2.3715x; 1.0684x over previous
//
#include <hip/hip_runtime.h>

#define DEV __device__ __forceinline__

typedef __bf16 bf16x8 __attribute__((ext_vector_type(8)));
typedef float f32x4 __attribute__((ext_vector_type(4)));

// ---- constants ----
#define BB 4
#define LL 2048
#define DMODEL 1024
#define DINNER 2048
#define NHEADS 16
#define HEADDIM 128
#define DSTATE 64
#define CONVDIM 2176
#define DINPROJ 4240
#define NCHUNK 32
#define ROWS (BB*LL)   // 8192

// ---- workspace offsets (bytes) ----
#define OF_A    ((size_t)0)            // 8192 f32
#define OF_ST   ((size_t)32768)        // 2 f32
#define OF_P    ((size_t)65536)        // 4240 f32
#define OF_Q    ((size_t)98304)        // 4240 f32
#define OF_WO   ((size_t)131072)       // 4 MB
#define OF_BC   ((size_t)4325376)      // 8192*128*2 = 2 MB (B|C bf16 per row)
#define OF_Y    ((size_t)50331648)     // 33.5 MB bf16
#define OF_YBF  ((size_t)100663296)    // 33.5 MB bf16
#define OF_SP   ((size_t)150994944)    // 33.5 MB bf16
#define OF_ACS  ((size_t)190840832)    // 512 KB
#define OF_ECS  ((size_t)191365120)    // 8 KB

DEV void gload_lds16(const void* g, void* l) {
  __builtin_amdgcn_global_load_lds((const __attribute__((address_space(1))) void*)g,
                                   (__attribute__((address_space(3))) void*)l, 16, 0, 0);
}

// XOR-swizzled byte address within a [R][64] bf16 tile (rows = 128 B).
DEV char* swaddr(char* base, int r, int c) {
  return base + r * 128 + (((c) * 2) ^ (((r) & 7) << 4));
}

DEV float fsilu(float v) {
  return v * __builtin_amdgcn_rcpf(1.f + __expf(-v));
}

// conv1d+silu for channel ch (conv-space), given a-window av[4] and mask mk[4]
DEV float convsilu(int ch, const float* __restrict__ conv_w, const float* __restrict__ conv_b,
                   const float* __restrict__ p, const float* __restrict__ q,
                   const float av[4], const float mk[4]) {
  f32x4 w4 = *(const f32x4*)(conv_w + ch * 4);
  float sa = av[0] * w4[0] + av[1] * w4[1] + av[2] * w4[2] + av[3] * w4[3];
  float sm = mk[0] * w4[0] + mk[1] * w4[1] + mk[2] * w4[2] + mk[3] * w4[3];
  float val = conv_b[ch] + q[DINNER + ch] * sm + p[DINNER + ch] * sa;
  return fsilu(val);
}

// ---- S0: w_embed stats (1 block) ----
__global__ __launch_bounds__(256) void stats_kernel(
    const float* __restrict__ w, float* __restrict__ st)
{
  int t = threadIdx.x;
  float s = 0.f, s2 = 0.f;
  #pragma unroll
  for (int j = 0; j < 4; j++) { float v = w[t + 256 * j]; s += v; s2 += v * v; }
  #pragma unroll
  for (int m = 32; m; m >>= 1) { s += __shfl_xor(s, m); s2 += __shfl_xor(s2, m); }
  __shared__ float rs[4], rs2[4];
  if ((t & 63) == 0) { rs[t >> 6] = s; rs2[t >> 6] = s2; }
  __syncthreads();
  if (t == 0) {
    float S = rs[0] + rs[1] + rs[2] + rs[3];
    float S2 = rs2[0] + rs2[1] + rs2[2] + rs2[3];
    float mu = S * (1.f / DMODEL);
    st[0] = mu;
    st[1] = S2 * (1.f / DMODEL) - mu * mu;
  }
}

// ---- S1: per-row scalar a_r = x * rsqrt(x^2*var_w + eps) ----
__global__ __launch_bounds__(256) void prep_a_kernel(
    const float* __restrict__ x, const float* __restrict__ st, float* __restrict__ a)
{
  int r = blockIdx.x * 256 + threadIdx.x;
  float varw = st[1];
  float xv = x[r];
  a[r] = xv * rsqrtf(xv * xv * varw + 1e-5f);
}

// ---- S2: GEMV p = ((w-wbar)*g) @ W_in^T ; q = beta @ W_in^T (f32x4 loads) ----
__global__ __launch_bounds__(256) void gemv_kernel(
    const float* __restrict__ w, const float* __restrict__ g,
    const float* __restrict__ beta, const float* __restrict__ st,
    const float* __restrict__ W, float* __restrict__ p, float* __restrict__ q)
{
  int t = threadIdx.x;
  int j = blockIdx.x * 16 + (t >> 4);
  int l16 = t & 15;
  float wbar = st[0];
  const float* Wr = W + (size_t)j * DMODEL;
  float ap = 0.f, aq = 0.f;
  #pragma unroll 4
  for (int jj = 0; jj < 16; jj++) {
    int i = jj * 64 + l16 * 4;
    f32x4 Wv = *(const f32x4*)(Wr + i);
    f32x4 wv = *(const f32x4*)(w + i);
    f32x4 gv = *(const f32x4*)(g + i);
    f32x4 bv = *(const f32x4*)(beta + i);
    #pragma unroll
    for (int e = 0; e < 4; e++) {
      ap += (wv[e] - wbar) * gv[e] * Wv[e];
      aq += bv[e] * Wv[e];
    }
  }
  #pragma unroll
  for (int m = 8; m; m >>= 1) { ap += __shfl_xor(ap, m, 16); aq += __shfl_xor(aq, m, 16); }
  if (l16 == 0) { p[j] = ap; q[j] = aq; }
}

// ---- S3: W_out fp32 -> bf16 ----
__global__ __launch_bounds__(256) void convert_wo_kernel(
    const float* __restrict__ Wo, __bf16* __restrict__ Wob)
{
  const int NO = DMODEL * DINNER;
  for (int i = blockIdx.x * 256 + threadIdx.x; i < NO; i += gridDim.x * 256)
    Wob[i] = (__bf16)Wo[i];
}

// ---- S4: B|C per row (channels 2048..2175), computed once, shared by 16 heads ----
__global__ __launch_bounds__(256) void bc_kernel(
    const float* __restrict__ a, const float* __restrict__ p,
    const float* __restrict__ q, const float* __restrict__ conv_w,
    const float* __restrict__ conv_b, __bf16* __restrict__ BC)
{
  int g = blockIdx.x * 256 + threadIdx.x;   // ROWS*16
  if (g >= ROWS * 16) return;
  int cg = g & 15, row = g >> 4;
  int l = row & (LL - 1);
  float av[4], mk[4];
  #pragma unroll
  for (int k = 0; k < 4; k++) {
    int li = l + k - 3;
    bool v = li >= 0;
    av[k] = v ? a[row + k - 3] : 0.f;
    mk[k] = v ? 1.f : 0.f;
  }
  bf16x8 o;
  #pragma unroll
  for (int j = 0; j < 8; j++)
    o[j] = (__bf16)convsilu(DINNER + cg * 8 + j, conv_w, conv_b, p, q, av, mk);
  *(bf16x8*)(BC + (size_t)row * 128 + cg * 8) = o;
}

// ---- K5: per-chunk intra (MFMA); X conv inline, B/C from BC buffer ----
__global__ __launch_bounds__(256) void ssd_chunk_kernel(
    const float* __restrict__ a, const float* __restrict__ p,
    const float* __restrict__ q, const float* __restrict__ conv_w,
    const float* __restrict__ conv_b, const float* __restrict__ dt_bias,
    const float* __restrict__ A_log, const __bf16* __restrict__ BC,
    __bf16* __restrict__ Y, __bf16* __restrict__ S,
    float* __restrict__ acs, float* __restrict__ ecs)
{
  __shared__ __align__(16) char sm[49664];
  char* smC  = sm;
  char* smB  = sm + 8192;
  char* smBd = sm + 16384;
  char* smG  = sm + 24576;
  char* smX  = sm + 32768;
  float* sAcs = (float*)(sm + 49152);
  float* sDec = (float*)(sm + 49408);

  int bx = blockIdx.x;
  int c = bx & 31, h = (bx >> 5) & 15, b = bx >> 9;
  int t = threadIdx.x;
  int lane = t & 63, w = t >> 6;
  int row0 = b * LL + c * 64;

  // a-window + mask for this thread's row (lane)
  float av[4], mk[4];
  {
    int lg = c * 64 + lane;
    #pragma unroll
    for (int k = 0; k < 4; k++) {
      int li = lg + k - 3;
      bool v = li >= 0;
      av[k] = v ? a[b * LL + li] : 0.f;
      mk[k] = v ? 1.f : 0.f;
    }
  }

  // dt inline (exact fp32); av[3] = a at this row
  float vx = av[3] * p[DINNER + CONVDIM + h] + q[DINNER + CONVDIM + h] + dt_bias[h];
  float dtv = vx > 15.f ? vx : log1pf(__expf(vx));

  // B/C from precomputed buffer; keep B in f32 regs for BdT
  const __bf16* bcr = BC + (size_t)(row0 + lane) * 128;
  float bv[16];
  #pragma unroll
  for (int k = 0; k < 2; k++) {
    int c8 = w * 16 + 8 * k;
    bf16x8 vb = *(const bf16x8*)(bcr + c8);
    bf16x8 vc = *(const bf16x8*)(bcr + 64 + c8);
    #pragma unroll
    for (int j = 0; j < 8; j++) bv[8 * k + j] = (float)vb[j];
    *(bf16x8*)swaddr(smB, lane, c8) = vb;
    *(bf16x8*)swaddr(smC, lane, c8) = vc;
  }
  // X inline conv (scaled by dt -> LDS transpose)
  #pragma unroll
  for (int k = 0; k < 4; k++) {
    int p0 = w * 8 + 32 * k;
    #pragma unroll
    for (int j = 0; j < 8; j++) {
      float xv2 = convsilu(h * HEADDIM + p0 + j, conv_w, conv_b, p, q, av, mk);
      *(__bf16*)swaddr(smX, p0 + j, lane) = (__bf16)(xv2 * dtv);
    }
  }

  // wave 0: inclusive scan of dA -> Acs, dec
  if (t < 64) {
    float Ah = -__expf(A_log[h]);
    float cs = dtv * Ah;
    #pragma unroll
    for (int off = 1; off < 64; off <<= 1) {
      float o = __shfl_up(cs, off);
      if (lane >= off) cs += o;
    }
    float cend = __shfl(cs, 63);
    sAcs[lane] = cs;
    sDec[lane] = __expf(cend - cs);
    acs[(((size_t)b * NHEADS + h) * NCHUNK + c) * 64 + lane] = cs;
    if (lane == 63) ecs[((size_t)b * NHEADS + h) * NCHUNK + c] = __expf(cend);
  }
  __syncthreads();

  float decv = sDec[lane];
  #pragma unroll
  for (int k = 0; k < 2; k++) {
    int c8 = w * 16 + 8 * k;
    #pragma unroll
    for (int j = 0; j < 8; j++)
      *(__bf16*)swaddr(smBd, c8 + j, lane) = (__bf16)(bv[8 * k + j] * decv);
  }

  int lr = lane & 15, kb = (lane >> 4) * 8;
  int rl = 16 * w + (lane >> 4) * 4;

  {
    bf16x8 af[2];
    #pragma unroll
    for (int ks = 0; ks < 2; ks++)
      af[ks] = *(const bf16x8*)swaddr(smC, 16 * w + lr, ks * 32 + kb);
    f32x4 g[4] = {};
    #pragma unroll
    for (int nt = 0; nt < 4; nt++)
      #pragma unroll
      for (int ks = 0; ks < 2; ks++) {
        bf16x8 bm = *(const bf16x8*)swaddr(smB, 16 * nt + lr, ks * 32 + kb);
        g[nt] = __builtin_amdgcn_mfma_f32_16x16x32_bf16(af[ks], bm, g[nt], 0, 0, 0);
      }
    #pragma unroll
    for (int nt = 0; nt < 4; nt++)
      #pragma unroll
      for (int qq = 0; qq < 4; qq++) {
        int gl = rl + qq, gs = 16 * nt + lr;
        float val = (gl >= gs) ? g[nt][qq] * __expf(sAcs[gl] - sAcs[gs]) : 0.f;
        *(__bf16*)swaddr(smG, gl, gs) = (__bf16)val;
      }
  }
  __syncthreads();

  {
    bf16x8 af[2];
    #pragma unroll
    for (int ks = 0; ks < 2; ks++)
      af[ks] = *(const bf16x8*)swaddr(smG, 16 * w + lr, ks * 32 + kb);
    f32x4 y[8] = {};
    #pragma unroll
    for (int nt = 0; nt < 8; nt++)
      #pragma unroll
      for (int ks = 0; ks < 2; ks++) {
        bf16x8 bm = *(const bf16x8*)swaddr(smX, 16 * nt + lr, ks * 32 + kb);
        y[nt] = __builtin_amdgcn_mfma_f32_16x16x32_bf16(af[ks], bm, y[nt], 0, 0, 0);
      }
    #pragma unroll
    for (int nt = 0; nt < 8; nt++)
      #pragma unroll
      for (int qq = 0; qq < 4; qq++)
        Y[(size_t)(row0 + rl + qq) * DINNER + h * HEADDIM + 16 * nt + lr] = (__bf16)y[nt][qq];
  }

  {
    bf16x8 bfs[4][2];
    #pragma unroll
    for (int nt = 0; nt < 4; nt++)
      #pragma unroll
      for (int ks = 0; ks < 2; ks++)
        bfs[nt][ks] = *(const bf16x8*)swaddr(smBd, 16 * nt + lr, ks * 32 + kb);
    f32x4 s4[2][4] = {};
    #pragma unroll
    for (int mi = 0; mi < 2; mi++) {
      bf16x8 af[2];
      #pragma unroll
      for (int ks = 0; ks < 2; ks++)
        af[ks] = *(const bf16x8*)swaddr(smX, 32 * w + 16 * mi + lr, ks * 32 + kb);
      #pragma unroll
      for (int nt = 0; nt < 4; nt++)
        #pragma unroll
        for (int ks = 0; ks < 2; ks++)
          s4[mi][nt] = __builtin_amdgcn_mfma_f32_16x16x32_bf16(af[ks], bfs[nt][ks], s4[mi][nt], 0, 0, 0);
    }
    __bf16* Sp = S + (((size_t)b * NCHUNK + c) * NHEADS + h) * (HEADDIM * DSTATE);
    #pragma unroll
    for (int mi = 0; mi < 2; mi++)
      #pragma unroll
      for (int nt = 0; nt < 4; nt++)
        #pragma unroll
        for (int qq = 0; qq < 4; qq++) {
          int pp = 32 * w + 16 * mi + (lane >> 4) * 4 + qq;
          Sp[pp * DSTATE + 16 * nt + lr] = (__bf16)s4[mi][nt][qq];
        }
  }
}

// ---- K6: inter-chunk scan, in-place, vectorized bf16x8 ----
__global__ __launch_bounds__(256) void scan_kernel(
    __bf16* SP, const float* __restrict__ ecs)
{
  int t = blockIdx.x * 256 + threadIdx.x;       // 65536 threads
  int n8 = (t & 7) * 8, p = (t >> 3) & 127, h = (t >> 10) & 15, b = t >> 14;
  const float* ep = ecs + ((size_t)b * NHEADS + h) * NCHUNK;
  float P[8] = {};
  size_t base = (((size_t)b * NCHUNK * NHEADS + h) * (HEADDIM * DSTATE)) + (size_t)p * DSTATE + n8;
  const size_t cstride = (size_t)NHEADS * HEADDIM * DSTATE;
  for (int c = 0; c < NCHUNK; c++) {
    __bf16* ptr = SP + base + (size_t)c * cstride;
    bf16x8 s = *(const bf16x8*)ptr;
    bf16x8 o;
    float e = ep[c];
    #pragma unroll
    for (int j = 0; j < 8; j++) {
      o[j] = (__bf16)P[j];
      P[j] = e * P[j] + (float)s[j];
    }
    *(bf16x8*)ptr = o;
  }
}

// ---- K7 (MFMA): Y += exp(Acs[l]) * (C @ P^T) + D * x; C from BC, x inline ----
__global__ __launch_bounds__(256) void ssd_off_kernel(
    const float* __restrict__ a, const float* __restrict__ p,
    const float* __restrict__ q, const float* __restrict__ conv_w,
    const float* __restrict__ conv_b, const __bf16* __restrict__ BC,
    const __bf16* __restrict__ P,
    const float* __restrict__ acs, const float* __restrict__ Dp,
    __bf16* __restrict__ Y)
{
  __shared__ __align__(16) char sm[25408];
  char* smC = sm;
  char* smP = sm + 8192;
  float* eA = (float*)(sm + 24576);
  float* sA = (float*)(sm + 24832);   // a-window: sA[i] = a[row0 + i - 3]
  int bx = blockIdx.x;
  int c = bx & 31, h = (bx >> 5) & 15, b = bx >> 9;
  int t = threadIdx.x;
  int lane = t & 63, w = t >> 6;
  int row0 = b * LL + c * 64;

  // C tile from BC buffer
  {
    const __bf16* bcr = BC + (size_t)(row0 + lane) * 128;
    #pragma unroll
    for (int k = 0; k < 2; k++) {
      int c8 = w * 16 + 8 * k;
      bf16x8 vc = *(const bf16x8*)(bcr + 64 + c8);
      *(bf16x8*)swaddr(smC, lane, c8) = vc;
    }
  }
  if (t < 67) {
    int li = c * 64 + t - 3;
    sA[t] = (li >= 0) ? a[b * LL + li] : 0.f;
  }
  const __bf16* Pp = P + (((size_t)b * NCHUNK + c) * NHEADS + h) * (HEADDIM * DSTATE);
  #pragma unroll
  for (int k = 0; k < 4; k++) {
    int qg = t + 256 * k;
    int pr = qg >> 3, c8 = (qg & 7) * 8;
    bf16x8 v = *(const bf16x8*)(Pp + pr * DSTATE + c8);
    *(bf16x8*)swaddr(smP, pr, c8) = v;
  }
  if (t < 64) eA[t] = __expf(acs[(((size_t)b * NHEADS + h) * NCHUNK + c) * 64 + t]);
  __syncthreads();

  int lr = lane & 15, kb = (lane >> 4) * 8;
  bf16x8 af[2];
  #pragma unroll
  for (int ks = 0; ks < 2; ks++)
    af[ks] = *(const bf16x8*)swaddr(smC, 16 * w + lr, ks * 32 + kb);
  f32x4 y[8] = {};
  #pragma unroll
  for (int nt = 0; nt < 8; nt++)
    #pragma unroll
    for (int ks = 0; ks < 2; ks++) {
      bf16x8 bm = *(const bf16x8*)swaddr(smP, 16 * nt + lr, ks * 32 + kb);
      y[nt] = __builtin_amdgcn_mfma_f32_16x16x32_bf16(af[ks], bm, y[nt], 0, 0, 0);
    }
  float Dh = Dp[h];
  int rl = 16 * w + (lane >> 4) * 4;
  #pragma unroll
  for (int nt = 0; nt < 8; nt++) {
    int ch = h * HEADDIM + 16 * nt + lr;
    f32x4 w4 = *(const f32x4*)(conv_w + ch * 4);
    float cb = conv_b[ch], px = p[DINNER + ch], qx = q[DINNER + ch];
    #pragma unroll
    for (int qq = 0; qq < 4; qq++) {
      int l = rl + qq;
      float sa = sA[l] * w4[0] + sA[l + 1] * w4[1] + sA[l + 2] * w4[2] + sA[l + 3] * w4[3];
      float smv;
      if (c > 0) smv = w4[0] + w4[1] + w4[2] + w4[3];
      else {
        smv = w4[3];
        #pragma unroll
        for (int k = 0; k < 3; k++) if (l + k >= 3) smv += w4[k];
      }
      float xsv = fsilu(cb + qx * smv + px * sa);
      size_t yi = (size_t)(row0 + l) * DINNER + ch;
      Y[yi] = (__bf16)((float)Y[yi] + eA[l] * y[nt][qq] + Dh * xsv);
    }
  }
}

// ---- K8: y *= silu(z), z from rank-1; RMSNorm; -> bf16 ----
__global__ __launch_bounds__(256) void gate_norm_kernel(
    const __bf16* __restrict__ Y, const float* __restrict__ a,
    const float* __restrict__ p, const float* __restrict__ q,
    const float* __restrict__ rms_w, __bf16* __restrict__ ybf)
{
  int row = blockIdx.x, t = threadIdx.x;
  float ar = a[row];
  float v[8]; float ss = 0.f;
  #pragma unroll
  for (int j = 0; j < 8; j++) {
    int i = t + j * 256;
    float zv = ar * p[i] + q[i];
    float yv = (float)Y[(size_t)row * DINNER + i];
    float g = yv * fsilu(zv);
    v[j] = g; ss += g * g;
  }
  #pragma unroll
  for (int m = 32; m; m >>= 1) ss += __shfl_xor(ss, m);
  __shared__ float red[4];
  if ((t & 63) == 0) red[t >> 6] = ss;
  __syncthreads();
  float tot = red[0] + red[1] + red[2] + red[3];
  float r = rsqrtf(tot * (1.f / DINNER) + 1e-5f);
  #pragma unroll
  for (int j = 0; j < 8; j++) {
    int i = t + j * 256;
    ybf[(size_t)row * DINNER + i] = (__bf16)(v[j] * r * rms_w[i]);
  }
}

// ---- K9: out_proj 256x128-tile GEMM, grid = 32x8 = 256 blocks ----
__global__ __launch_bounds__(512, 2) void gemm_op_kernel(
    const __bf16* __restrict__ A, const __bf16* __restrict__ Bt,
    float* __restrict__ C, int K, int N)
{
  extern __shared__ char sm[];          // A: 4 x 16KB @0, B: 4 x 8KB @65536
  const int t = threadIdx.x;
  const int lane = t & 63, w = t >> 6;
  const int wr = w >> 1, wc = w & 1;

  int nbn = gridDim.x;                  // 8
  int nwg = nbn * gridDim.y;            // 256
  int lid = blockIdx.y * nbn + blockIdx.x;
  int wg = (lid & 7) * (nwg >> 3) + (lid >> 3);
  int m0 = (wg / nbn) * 256, n0 = (wg % nbn) * 128;

  int r0, c0, r1, c1;
  {
    int y0 = t * 16, pg0 = y0 >> 7;
    int in0 = (y0 & 127) ^ ((pg0 & 7) << 4);
    r0 = pg0 * 2 + (in0 >> 6); c0 = in0 & 63;
    int y1 = 8192 + t * 16, pg1 = y1 >> 7;
    int in1 = (y1 & 127) ^ ((pg1 & 7) << 4);
    r1 = pg1 * 2 + (in1 >> 6); c1 = in1 & 63;
  }
  const char* pA0 = (const char*)A + (size_t)(m0 + r0) * (2 * K) + c0;
  const char* pA1 = (const char*)A + (size_t)(m0 + r1) * (2 * K) + c1;
  const char* pB0 = (const char*)Bt + (size_t)(n0 + r0) * (2 * K) + c0;

  const int lr = lane & 15, kg = lane >> 4;
  int rA = wr * 64 + lr, pgA = rA >> 1;
  const int offA = pgA * 128 + ((((rA & 1) << 6) | (kg << 4)) ^ ((pgA & 7) << 4));
  int rB = wc * 64 + lr, pgB = rB >> 1;
  const int offB = pgB * 128 + ((((rB & 1) << 6) | (kg << 4)) ^ ((pgB & 7) << 4));

  f32x4 acc[4][4] = {};
  const int KT = K >> 5;

  #define STG(slot) do { \
    char* la_ = sm + (slot) * 16384; \
    char* lb_ = sm + 65536 + (slot) * 8192; \
    gload_lds16(pA0, la_ + t * 16); \
    gload_lds16(pA1, la_ + 8192 + t * 16); \
    gload_lds16(pB0, lb_ + t * 16); \
    pA0 += 64; pA1 += 64; pB0 += 64; \
  } while (0)

  STG(0); STG(1); STG(2);
  asm volatile("s_waitcnt vmcnt(6)" ::: "memory");
  __builtin_amdgcn_sched_barrier(0);
  __builtin_amdgcn_s_barrier();

  for (int kt = 0; kt < KT; ++kt) {
    int s = kt & 3;
    if (kt + 3 < KT) STG((kt + 3) & 3);
    const char* sa = sm + s * 16384;
    const char* sb = sm + 65536 + s * 8192;
    bf16x8 af[4], bfr[4];
    #pragma unroll
    for (int m = 0; m < 4; m++) af[m] = *(const bf16x8*)(sa + offA + m * 1024);
    #pragma unroll
    for (int n = 0; n < 4; n++) bfr[n] = *(const bf16x8*)(sb + offB + n * 1024);
    __builtin_amdgcn_s_setprio(1);
    #pragma unroll
    for (int m = 0; m < 4; m++)
      #pragma unroll
      for (int n = 0; n < 4; n++)
        acc[m][n] = __builtin_amdgcn_mfma_f32_16x16x32_bf16(af[m], bfr[n], acc[m][n], 0, 0, 0);
    __builtin_amdgcn_s_setprio(0);
    if (kt + 3 < KT)      { asm volatile("s_waitcnt vmcnt(6)" ::: "memory"); }
    else if (kt + 2 < KT) { asm volatile("s_waitcnt vmcnt(3)" ::: "memory"); }
    else if (kt + 1 < KT) { asm volatile("s_waitcnt vmcnt(0)" ::: "memory"); }
    __builtin_amdgcn_sched_barrier(0);
    __builtin_amdgcn_s_barrier();
  }
  #undef STG

  #pragma unroll
  for (int m = 0; m < 4; m++)
    #pragma unroll
    for (int n = 0; n < 4; n++)
      #pragma unroll
      for (int qq = 0; qq < 4; qq++) {
        int row = m0 + wr * 64 + m * 16 + kg * 4 + qq;
        int col = n0 + wc * 64 + n * 16 + lr;
        C[(size_t)row * N + col] = acc[m][n][qq];
      }
}

extern "C" void kernel_launch(void* const* d_in, const int* in_sizes, int n_in,
                              void* d_out, int out_size, void* d_ws, size_t ws_size,
                              hipStream_t stream) {
  const float* x       = (const float*)d_in[0];
  const float* w_embed = (const float*)d_in[1];
  const float* ln_g    = (const float*)d_in[2];
  const float* ln_b    = (const float*)d_in[3];
  const float* W_in    = (const float*)d_in[4];
  const float* conv_w  = (const float*)d_in[5];
  const float* conv_b  = (const float*)d_in[6];
  const float* dt_bias = (const float*)d_in[7];
  const float* A_log   = (const float*)d_in[8];
  const float* Dp      = (const float*)d_in[9];
  const float* rms_w   = (const float*)d_in[10];
  const float* W_out   = (const float*)d_in[11];
  char* ws = (char*)d_ws;
  float*  aR   = (float*)(ws + OF_A);
  float*  st   = (float*)(ws + OF_ST);
  float*  pV   = (float*)(ws + OF_P);
  float*  qV   = (float*)(ws + OF_Q);
  __bf16* Wob  = (__bf16*)(ws + OF_WO);
  __bf16* BCb  = (__bf16*)(ws + OF_BC);
  __bf16* Ybf  = (__bf16*)(ws + OF_Y);
  __bf16* ybf  = (__bf16*)(ws + OF_YBF);
  __bf16* SP   = (__bf16*)(ws + OF_SP);
  float*  acs  = (float*)(ws + OF_ACS);
  float*  ecs  = (float*)(ws + OF_ECS);
  float*  out  = (float*)d_out;

  hipFuncSetAttribute((const void*)gemm_op_kernel,
                      hipFuncAttributeMaxDynamicSharedMemorySize, 98304);

  stats_kernel<<<1, 256, 0, stream>>>(w_embed, st);
  prep_a_kernel<<<ROWS / 256, 256, 0, stream>>>(x, st, aR);
  gemv_kernel<<<DINPROJ / 16, 256, 0, stream>>>(w_embed, ln_g, ln_b, st, W_in, pV, qV);
  convert_wo_kernel<<<1024, 256, 0, stream>>>(W_out, Wob);
  bc_kernel<<<(ROWS * 16) / 256, 256, 0, stream>>>(aR, pV, qV, conv_w, conv_b, BCb);
  ssd_chunk_kernel<<<BB * NHEADS * NCHUNK, 256, 0, stream>>>(
      aR, pV, qV, conv_w, conv_b, dt_bias, A_log, BCb, Ybf, SP, acs, ecs);
  scan_kernel<<<(BB * NHEADS * HEADDIM * DSTATE / 8) / 256, 256, 0, stream>>>(SP, ecs);
  ssd_off_kernel<<<BB * NHEADS * NCHUNK, 256, 0, stream>>>(
      aR, pV, qV, conv_w, conv_b, BCb, SP, acs, Dp, Ybf);
  gate_norm_kernel<<<ROWS, 256, 0, stream>>>(Ybf, aR, pV, qV, rms_w, ybf);
  gemm_op_kernel<<<dim3(8, 32), 512, 98304, stream>>>(ybf, Wob, out, DINNER, DMODEL);
}